// Round 11
// baseline (386.032 us; speedup 1.0000x reference)
//
#include <hip/hip_runtime.h>

#define N_NODES 50000
#define N_EDGES 800000
#define IN_C 128
#define HID_C 256
#define OUT_C 128
#define NBLK 196  // ceil(N_NODES / 256)

typedef __attribute__((ext_vector_type(8))) short short8v;  // 8 bf16
typedef __attribute__((ext_vector_type(4))) float f32x4;

static __device__ __forceinline__ unsigned short f2bf(float f) {
  unsigned int u = __float_as_uint(f);
  unsigned int r = (u + 0x7fffu + ((u >> 16) & 1u)) >> 16;  // RNE
  return (unsigned short)r;
}
static __device__ __forceinline__ float bf2f(unsigned short h) {
  return __uint_as_float(((unsigned int)h) << 16);
}

// ---------------------------------------------------------------------------
// Edge conversion (int32/int64 auto-detect) fused with dst-degree histogram.
// ---------------------------------------------------------------------------
__global__ __launch_bounds__(256) void deg_zero_k(int* __restrict__ deg) {
  const int i = blockIdx.x * 256 + threadIdx.x;
  if (i < N_NODES) deg[i] = 0;
}

__global__ __launch_bounds__(256) void convert_count_k(const int* __restrict__ ei,
                                                       int* __restrict__ src,
                                                       int* __restrict__ dst,
                                                       int* __restrict__ deg) {
  __shared__ int s_is64;
  if (threadIdx.x == 0) {
    int nz = 0;
#pragma unroll
    for (int k = 0; k < 64; ++k) nz |= ei[2 * k + 1];
    s_is64 = (nz == 0) ? 1 : 0;
  }
  __syncthreads();
  const int is64 = s_is64;
  const int e = blockIdx.x * 256 + threadIdx.x;
  if (e < N_EDGES) {
    int s, d;
    if (is64) {
      s = ei[2 * e];
      d = ei[2 * (N_EDGES + e)];
    } else {
      s = ei[e];
      d = ei[N_EDGES + e];
    }
    src[e] = s;
    dst[e] = d;
    atomicAdd(&deg[d], 1);
  }
}

// ---------------------------------------------------------------------------
// Parallel 3-phase exclusive scan over deg (bsum / bscan / bfinal+dinv).
// ---------------------------------------------------------------------------
__global__ __launch_bounds__(256) void bsum_k(const int* __restrict__ deg,
                                              int* __restrict__ bsum) {
  const int i = blockIdx.x * 256 + threadIdx.x;
  int v = (i < N_NODES) ? deg[i] : 0;
#pragma unroll
  for (int off = 32; off > 0; off >>= 1) v += __shfl_down(v, off, 64);
  __shared__ int ws[4];
  if ((threadIdx.x & 63) == 0) ws[threadIdx.x >> 6] = v;
  __syncthreads();
  if (threadIdx.x == 0) bsum[blockIdx.x] = ws[0] + ws[1] + ws[2] + ws[3];
}

__global__ __launch_bounds__(256) void bscan_k(const int* __restrict__ bsum,
                                               int* __restrict__ boff) {
  __shared__ int s[256];
  const int t = threadIdx.x;
  const int v = (t < NBLK) ? bsum[t] : 0;
  s[t] = v;
  __syncthreads();
  for (int off = 1; off < 256; off <<= 1) {
    const int tmp = (t >= off) ? s[t - off] : 0;
    __syncthreads();
    s[t] += tmp;
    __syncthreads();
  }
  if (t < NBLK) boff[t] = s[t] - v;
}

__global__ __launch_bounds__(256) void bfinal_k(const int* __restrict__ deg,
                                                const int* __restrict__ boff,
                                                int* __restrict__ rowstart,
                                                int* __restrict__ cursor,
                                                float* __restrict__ dinv) {
  __shared__ int s[256];
  const int t = threadIdx.x;
  const int i = blockIdx.x * 256 + t;
  const int d = (i < N_NODES) ? deg[i] : 0;
  s[t] = d;
  __syncthreads();
  for (int off = 1; off < 256; off <<= 1) {
    const int tmp = (t >= off) ? s[t - off] : 0;
    __syncthreads();
    s[t] += tmp;
    __syncthreads();
  }
  const int run = boff[blockIdx.x] + s[t] - d;
  if (i < N_NODES) {
    rowstart[i] = run;
    cursor[i] = run;
    dinv[i] = rsqrtf((float)d + 1.0f);
    if (i == N_NODES - 1) rowstart[N_NODES] = run + d;
  }
}

__global__ __launch_bounds__(256) void fill_csr_k(const int* __restrict__ src,
                                                  const int* __restrict__ dst,
                                                  int* __restrict__ cursor,
                                                  int* __restrict__ csr_src) {
  const int e = blockIdx.x * 256 + threadIdx.x;
  if (e < N_EDGES) {
    const int pos = atomicAdd(&cursor[dst[e]], 1);
    csr_src[pos] = src[e];
  }
}

// ---------------------------------------------------------------------------
// Weight split: fp32 -> (bf16 hi, bf16 lo) with hi+lo ~ 16 mantissa bits.
// ---------------------------------------------------------------------------
__global__ __launch_bounds__(256) void split_k(const float* __restrict__ in,
                                               unsigned short* __restrict__ hi,
                                               unsigned short* __restrict__ lo,
                                               int n) {
  const int i = blockIdx.x * 256 + threadIdx.x;
  if (i < n) {
    const float v = in[i];
    const unsigned short h = f2bf(v);
    hi[i] = h;
    lo[i] = f2bf(v - bf2f(h));
  }
}

// ---------------------------------------------------------------------------
// MFMA GEMM via bf16-split 3-pass: H = X*W^T (X:[N][K], W:[M][K] as hi/lo bf16).
// Block: 256 thr = 4 waves x 16 nodes; 64 m-chans per block (4 MFMA tiles).
// A frag: lane l -> X[row=l&15][k=(l>>4)*8+j]; B frag: W[m=l&15][same k].
// D: col(m)=l&15, row(n)=(l>>4)*4+reg  [verified m89 mapping].
// SPLIT_OUT: epilogue bias+relu then store split bf16 (hi,lo). Else fp32.
// ---------------------------------------------------------------------------
template <int K, int MTOT, bool SPLIT_OUT>
__global__ __launch_bounds__(256) void gemm_mfma_k(
    const unsigned short* __restrict__ Xhi, const unsigned short* __restrict__ Xlo,
    const unsigned short* __restrict__ Whi, const unsigned short* __restrict__ Wlo,
    const float* __restrict__ bias, unsigned short* __restrict__ outHi,
    unsigned short* __restrict__ outLo, float* __restrict__ outF) {
  const int w = threadIdx.x >> 6;
  const int l = threadIdx.x & 63;
  const int nbase = blockIdx.x * 64 + w * 16;
  const int m0 = blockIdx.y * 64;
  const int arow_ = nbase + (l & 15);
  const int arow = (arow_ < N_NODES) ? arow_ : (N_NODES - 1);
  const int kg = (l >> 4) * 8;
  const int bcol = l & 15;

  f32x4 acc[4];
#pragma unroll
  for (int mt = 0; mt < 4; ++mt) acc[mt] = {0.0f, 0.0f, 0.0f, 0.0f};

#pragma unroll
  for (int ks = 0; ks < K / 32; ++ks) {
    const int ko = ks * 32 + kg;
    const short8v aHi = *(const short8v*)(Xhi + (long)arow * K + ko);
    const short8v aLo = *(const short8v*)(Xlo + (long)arow * K + ko);
#pragma unroll
    for (int mt = 0; mt < 4; ++mt) {
      const long wro = (long)(m0 + mt * 16 + bcol) * K + ko;
      const short8v bHi = *(const short8v*)(Whi + wro);
      const short8v bLo = *(const short8v*)(Wlo + wro);
      acc[mt] = __builtin_amdgcn_mfma_f32_16x16x32_bf16(aHi, bHi, acc[mt], 0, 0, 0);
      acc[mt] = __builtin_amdgcn_mfma_f32_16x16x32_bf16(aHi, bLo, acc[mt], 0, 0, 0);
      acc[mt] = __builtin_amdgcn_mfma_f32_16x16x32_bf16(aLo, bHi, acc[mt], 0, 0, 0);
    }
  }

  const int rbase = nbase + (l >> 4) * 4;
#pragma unroll
  for (int mt = 0; mt < 4; ++mt) {
    const int m = m0 + mt * 16 + bcol;
    const float bm = SPLIT_OUT ? bias[m] : 0.0f;
#pragma unroll
    for (int r = 0; r < 4; ++r) {
      const int n = rbase + r;
      if (n < N_NODES) {
        float v = acc[mt][r];
        if (SPLIT_OUT) {
          v = fmaxf(v + bm, 0.0f);  // bias + relu before split
          const unsigned short h = f2bf(v);
          outHi[(long)n * MTOT + m] = h;
          outLo[(long)n * MTOT + m] = f2bf(v - bf2f(h));
        } else {
          outF[(long)n * MTOT + m] = v;
        }
      }
    }
  }
}

// ---------------------------------------------------------------------------
// Gather-aggregate (one wave per destination node), C=128 -> 2 floats/lane.
// OUT_SPLIT: write bf16 hi/lo pair (feeds MFMA GEMM). Else fp32 (+bias).
// ---------------------------------------------------------------------------
template <int C, bool HAS_BIAS, bool OUT_SPLIT>
__global__ __launch_bounds__(256) void gather_k(const int* __restrict__ rowstart,
                                                const int* __restrict__ csr_src,
                                                const float* __restrict__ dinv,
                                                const float* __restrict__ h,
                                                const float* __restrict__ bias,
                                                float* __restrict__ out,
                                                unsigned short* __restrict__ outHi,
                                                unsigned short* __restrict__ outLo) {
  const int v = (blockIdx.x * 256 + threadIdx.x) >> 6;
  if (v >= N_NODES) return;
  const int lane = threadIdx.x & 63;
  constexpr int LPE = C / 64;  // 2
  const int rs = rowstart[v];
  const int re = rowstart[v + 1];
  const float dv = dinv[v];

  float acc[LPE];
#pragma unroll
  for (int i = 0; i < LPE; ++i) acc[i] = 0.0f;

  int e = rs;
  for (; e + 1 < re; e += 2) {
    const int s0 = csr_src[e];
    const int s1 = csr_src[e + 1];
    const float n0 = dv * dinv[s0];
    const float n1 = dv * dinv[s1];
    const float2 a = *(const float2*)(h + (long)s0 * C + lane * LPE);
    const float2 b = *(const float2*)(h + (long)s1 * C + lane * LPE);
    acc[0] += n0 * a.x + n1 * b.x;
    acc[1] += n0 * a.y + n1 * b.y;
  }
  if (e < re) {
    const int s0 = csr_src[e];
    const float n0 = dv * dinv[s0];
    const float2 a = *(const float2*)(h + (long)s0 * C + lane * LPE);
    acc[0] += n0 * a.x;
    acc[1] += n0 * a.y;
  }

  const float s2 = dv * dv;
  const float2 hv = *(const float2*)(h + (long)v * C + lane * LPE);
  float2 o = {s2 * hv.x + acc[0], s2 * hv.y + acc[1]};
  if (HAS_BIAS) {
    const float2 bv = *(const float2*)(bias + lane * LPE);
    o.x += bv.x;
    o.y += bv.y;
  }
  if (OUT_SPLIT) {
    const unsigned short h0 = f2bf(o.x), h1 = f2bf(o.y);
    const unsigned short l0 = f2bf(o.x - bf2f(h0)), l1 = f2bf(o.y - bf2f(h1));
    *(unsigned int*)(outHi + (long)v * C + lane * LPE) =
        (unsigned int)h0 | ((unsigned int)h1 << 16);
    *(unsigned int*)(outLo + (long)v * C + lane * LPE) =
        (unsigned int)l0 | ((unsigned int)l1 << 16);
  } else {
    *(float2*)(out + (long)v * C + lane * LPE) = o;
  }
}

// ---------------------------------------------------------------------------
extern "C" void kernel_launch(void* const* d_in, const int* in_sizes, int n_in,
                              void* d_out, int out_size, void* d_ws, size_t ws_size,
                              hipStream_t stream) {
  (void)in_sizes; (void)n_in; (void)out_size; (void)ws_size;

  const float* x  = (const float*)d_in[0];
  const int*   ei = (const int*)d_in[1];
  const float* W1 = (const float*)d_in[2];
  const float* b1 = (const float*)d_in[3];
  const float* W2 = (const float*)d_in[4];
  const float* b2 = (const float*)d_in[5];
  float* out = (float*)d_out;

  // Workspace layout (bytes, 16B-aligned):
  char* ws = (char*)d_ws;
  int*   src      = (int*)(ws + 0);            //  3.2 MB
  int*   dst      = (int*)(ws + 3200000);      //  3.2 MB
  int*   csr_src  = (int*)(ws + 6400000);      //  3.2 MB
  int*   deg      = (int*)(ws + 9600000);      //  0.2 MB
  int*   rowstart = (int*)(ws + 9800000);      //  0.2 MB (N+1)
  int*   cursor   = (int*)(ws + 10000016);     //  0.2 MB
  float* dinv     = (float*)(ws + 10200016);   //  0.2 MB
  int*   bsum     = (int*)(ws + 10400016);
  int*   boff     = (int*)(ws + 10401040);
  unsigned short* w1hi = (unsigned short*)(ws + 10500000);  // 64 KB each
  unsigned short* w1lo = (unsigned short*)(ws + 10565536);
  unsigned short* w2hi = (unsigned short*)(ws + 10631072);
  unsigned short* w2lo = (unsigned short*)(ws + 10696608);
  unsigned short* aggx_hi = (unsigned short*)(ws + 10800000);  // 12.8 MB
  unsigned short* aggx_lo = (unsigned short*)(ws + 23600000);  // 12.8 MB
  float*          h2      = (float*)(ws + 10800000);  // 25.6 MB, aliases aggx (dead)
  unsigned short* h1hi    = (unsigned short*)(ws + 36400000);  // 25.6 MB
  unsigned short* h1lo    = (unsigned short*)(ws + 62000000);  // 25.6 MB

  const int EB  = (N_EDGES + 255) / 256;  // 3125
  const int GB  = (N_NODES + 3) / 4;      // gather: 1 node/wave
  const int NT64 = (N_NODES + 63) / 64;   // 782 node-tiles for MFMA GEMM

  // ---- Graph preprocessing: CSR by destination + dinv ----
  deg_zero_k<<<NBLK, 256, 0, stream>>>(deg);
  convert_count_k<<<EB, 256, 0, stream>>>(ei, src, dst, deg);
  bsum_k<<<NBLK, 256, 0, stream>>>(deg, bsum);
  bscan_k<<<1, 256, 0, stream>>>(bsum, boff);
  bfinal_k<<<NBLK, 256, 0, stream>>>(deg, boff, rowstart, cursor, dinv);
  fill_csr_k<<<EB, 256, 0, stream>>>(src, dst, cursor, csr_src);

  // ---- Weight splits (tiny) ----
  split_k<<<(HID_C * IN_C + 255) / 256, 256, 0, stream>>>(W1, w1hi, w1lo, HID_C * IN_C);
  split_k<<<(OUT_C * HID_C + 255) / 256, 256, 0, stream>>>(W2, w2hi, w2lo, OUT_C * HID_C);

  // ---- Layer 1: aggx = agg(x) (split out); h1 = relu(aggx@W1^T + b1) (split out)
  gather_k<IN_C, false, true><<<GB, 256, 0, stream>>>(
      rowstart, csr_src, dinv, x, nullptr, nullptr, aggx_hi, aggx_lo);
  gemm_mfma_k<IN_C, HID_C, true><<<dim3(NT64, HID_C / 64), 256, 0, stream>>>(
      aggx_hi, aggx_lo, w1hi, w1lo, b1, h1hi, h1lo, nullptr);

  // ---- Layer 2: h2 = h1@W2^T (fp32 out); out = agg(h2) + b2
  gemm_mfma_k<HID_C, OUT_C, false><<<dim3(NT64, OUT_C / 64), 256, 0, stream>>>(
      h1hi, h1lo, w2hi, w2lo, nullptr, nullptr, nullptr, h2);
  gather_k<OUT_C, true, false><<<GB, 256, 0, stream>>>(
      rowstart, csr_src, dinv, h2, b2, out, nullptr, nullptr);
}

// Round 12
// 361.267 us; speedup vs baseline: 1.0686x; 1.0686x over previous
//
#include <hip/hip_runtime.h>

#define N_NODES 50000
#define N_EDGES 800000
#define IN_C 128
#define HID_C 256
#define OUT_C 128
#define NBLK 196  // ceil(N_NODES / 256)

typedef __attribute__((ext_vector_type(8))) short short8v;  // 8 bf16
typedef __attribute__((ext_vector_type(4))) float f32x4;

static __device__ __forceinline__ unsigned short f2bf(float f) {
  unsigned int u = __float_as_uint(f);
  unsigned int r = (u + 0x7fffu + ((u >> 16) & 1u)) >> 16;  // RNE
  return (unsigned short)r;
}
static __device__ __forceinline__ float bf2f(unsigned short h) {
  return __uint_as_float(((unsigned int)h) << 16);
}
// HL format: u32 = hi_bf16 | lo_bf16<<16, hi+lo ~= 16 mantissa bits of fp32.
static __device__ __forceinline__ unsigned int packHL(float v) {
  const unsigned short h = f2bf(v);
  const unsigned short l = f2bf(v - bf2f(h));
  return (unsigned int)h | ((unsigned int)l << 16);
}
static __device__ __forceinline__ void unpackHL(const unsigned int* __restrict__ p,
                                                short8v& hi, short8v& lo) {
  const uint4 a = *(const uint4*)p;
  const uint4 b = *(const uint4*)(p + 4);
  union { unsigned int u[4]; short8v s; } H, L;
  H.u[0] = (a.x & 0xffffu) | (a.y << 16);
  H.u[1] = (a.z & 0xffffu) | (a.w << 16);
  H.u[2] = (b.x & 0xffffu) | (b.y << 16);
  H.u[3] = (b.z & 0xffffu) | (b.w << 16);
  L.u[0] = (a.x >> 16) | (a.y & 0xffff0000u);
  L.u[1] = (a.z >> 16) | (a.w & 0xffff0000u);
  L.u[2] = (b.x >> 16) | (b.y & 0xffff0000u);
  L.u[3] = (b.z >> 16) | (b.w & 0xffff0000u);
  hi = H.s;
  lo = L.s;
}

// ---------------------------------------------------------------------------
// Edge conversion (int32/int64 auto-detect) fused with dst-degree histogram.
// ---------------------------------------------------------------------------
__global__ __launch_bounds__(256) void deg_zero_k(int* __restrict__ deg) {
  const int i = blockIdx.x * 256 + threadIdx.x;
  if (i < N_NODES) deg[i] = 0;
}

__global__ __launch_bounds__(256) void convert_count_k(const int* __restrict__ ei,
                                                       int* __restrict__ src,
                                                       int* __restrict__ dst,
                                                       int* __restrict__ deg) {
  __shared__ int s_is64;
  if (threadIdx.x == 0) {
    int nz = 0;
#pragma unroll
    for (int k = 0; k < 64; ++k) nz |= ei[2 * k + 1];
    s_is64 = (nz == 0) ? 1 : 0;
  }
  __syncthreads();
  const int is64 = s_is64;
  const int e = blockIdx.x * 256 + threadIdx.x;
  if (e < N_EDGES) {
    int s, d;
    if (is64) {
      s = ei[2 * e];
      d = ei[2 * (N_EDGES + e)];
    } else {
      s = ei[e];
      d = ei[N_EDGES + e];
    }
    src[e] = s;
    dst[e] = d;
    atomicAdd(&deg[d], 1);
  }
}

// ---------------------------------------------------------------------------
// Parallel 3-phase exclusive scan over deg (bsum / bscan / bfinal+dinv).
// ---------------------------------------------------------------------------
__global__ __launch_bounds__(256) void bsum_k(const int* __restrict__ deg,
                                              int* __restrict__ bsum) {
  const int i = blockIdx.x * 256 + threadIdx.x;
  int v = (i < N_NODES) ? deg[i] : 0;
#pragma unroll
  for (int off = 32; off > 0; off >>= 1) v += __shfl_down(v, off, 64);
  __shared__ int ws[4];
  if ((threadIdx.x & 63) == 0) ws[threadIdx.x >> 6] = v;
  __syncthreads();
  if (threadIdx.x == 0) bsum[blockIdx.x] = ws[0] + ws[1] + ws[2] + ws[3];
}

__global__ __launch_bounds__(256) void bscan_k(const int* __restrict__ bsum,
                                               int* __restrict__ boff) {
  __shared__ int s[256];
  const int t = threadIdx.x;
  const int v = (t < NBLK) ? bsum[t] : 0;
  s[t] = v;
  __syncthreads();
  for (int off = 1; off < 256; off <<= 1) {
    const int tmp = (t >= off) ? s[t - off] : 0;
    __syncthreads();
    s[t] += tmp;
    __syncthreads();
  }
  if (t < NBLK) boff[t] = s[t] - v;
}

__global__ __launch_bounds__(256) void bfinal_k(const int* __restrict__ deg,
                                                const int* __restrict__ boff,
                                                int* __restrict__ rowstart,
                                                int* __restrict__ cursor,
                                                float* __restrict__ dinv) {
  __shared__ int s[256];
  const int t = threadIdx.x;
  const int i = blockIdx.x * 256 + t;
  const int d = (i < N_NODES) ? deg[i] : 0;
  s[t] = d;
  __syncthreads();
  for (int off = 1; off < 256; off <<= 1) {
    const int tmp = (t >= off) ? s[t - off] : 0;
    __syncthreads();
    s[t] += tmp;
    __syncthreads();
  }
  const int run = boff[blockIdx.x] + s[t] - d;
  if (i < N_NODES) {
    rowstart[i] = run;
    cursor[i] = run;
    dinv[i] = rsqrtf((float)d + 1.0f);
    if (i == N_NODES - 1) rowstart[N_NODES] = run + d;
  }
}

__global__ __launch_bounds__(256) void fill_csr_k(const int* __restrict__ src,
                                                  const int* __restrict__ dst,
                                                  int* __restrict__ cursor,
                                                  int* __restrict__ csr_src) {
  const int e = blockIdx.x * 256 + threadIdx.x;
  if (e < N_EDGES) {
    const int pos = atomicAdd(&cursor[dst[e]], 1);
    csr_src[pos] = src[e];
  }
}

// ---------------------------------------------------------------------------
// Weight split: fp32 -> HL u32 (bf16 hi | bf16 lo << 16).
// ---------------------------------------------------------------------------
__global__ __launch_bounds__(256) void split_k(const float* __restrict__ in,
                                               unsigned int* __restrict__ hl,
                                               int n) {
  const int i = blockIdx.x * 256 + threadIdx.x;
  if (i < n) hl[i] = packHL(in[i]);
}

// ---------------------------------------------------------------------------
// MFMA GEMM, bf16-split 3-pass, HL-packed operands, SWAPPED operand order:
//   A-frag = W rows, B-frag = X rows  =>  D[row=m-within-16][col=n-within-16]
// so each lane's 4 acc regs = 4 CONSECUTIVE m for one n -> 16B vector stores.
// Frag layout (m89-verified): lane l holds operand row (l&15), k=(l>>4)*8+j.
// SPLIT_OUT: bias+relu then HL u32x4 store. Else fp32 float4 store.
// ---------------------------------------------------------------------------
template <int K, int MTOT, bool SPLIT_OUT>
__global__ __launch_bounds__(256) void gemm_mfma_k(
    const unsigned int* __restrict__ XHL, const unsigned int* __restrict__ WHL,
    const float* __restrict__ bias, unsigned int* __restrict__ outHL,
    float* __restrict__ outF) {
  const int w = threadIdx.x >> 6;
  const int l = threadIdx.x & 63;
  const int nbase = blockIdx.x * 64 + w * 16;
  const int m0 = blockIdx.y * 64;
  const int xr_ = nbase + (l & 15);
  const int xrow = (xr_ < N_NODES) ? xr_ : (N_NODES - 1);  // read clamp
  const int kg = (l >> 4) * 8;

  f32x4 acc[4];
#pragma unroll
  for (int mt = 0; mt < 4; ++mt) acc[mt] = {0.0f, 0.0f, 0.0f, 0.0f};

#pragma unroll
  for (int ks = 0; ks < K / 32; ++ks) {
    const int ko = ks * 32 + kg;
    short8v xHi, xLo;
    unpackHL(XHL + (long)xrow * K + ko, xHi, xLo);
#pragma unroll
    for (int mt = 0; mt < 4; ++mt) {
      short8v wHi, wLo;
      unpackHL(WHL + (long)(m0 + mt * 16 + (l & 15)) * K + ko, wHi, wLo);
      acc[mt] = __builtin_amdgcn_mfma_f32_16x16x32_bf16(wHi, xHi, acc[mt], 0, 0, 0);
      acc[mt] = __builtin_amdgcn_mfma_f32_16x16x32_bf16(wLo, xHi, acc[mt], 0, 0, 0);
      acc[mt] = __builtin_amdgcn_mfma_f32_16x16x32_bf16(wHi, xLo, acc[mt], 0, 0, 0);
    }
  }

  const int n = nbase + (l & 15);  // D col = B-row = node
  if (n >= N_NODES) return;
  const int mq0 = (l >> 4) * 4;  // D rows = 4 consecutive m
#pragma unroll
  for (int mt = 0; mt < 4; ++mt) {
    const int mq = m0 + mt * 16 + mq0;
    if (SPLIT_OUT) {
      const float4 bv = *(const float4*)(bias + mq);
      uint4 o;
      o.x = packHL(fmaxf(acc[mt][0] + bv.x, 0.0f));
      o.y = packHL(fmaxf(acc[mt][1] + bv.y, 0.0f));
      o.z = packHL(fmaxf(acc[mt][2] + bv.z, 0.0f));
      o.w = packHL(fmaxf(acc[mt][3] + bv.w, 0.0f));
      *(uint4*)(outHL + (long)n * MTOT + mq) = o;
    } else {
      const float4 o = {acc[mt][0], acc[mt][1], acc[mt][2], acc[mt][3]};
      *(float4*)(outF + (long)n * MTOT + mq) = o;
    }
  }
}

// ---------------------------------------------------------------------------
// Gather-aggregate (one wave per destination node), C=128 -> 2 floats/lane.
// 4-edge unroll: 4 independent row loads in flight.
// OUT_HL: write HL u32 pair (8B store, feeds MFMA GEMM). Else fp32 (+bias).
// ---------------------------------------------------------------------------
template <int C, bool HAS_BIAS, bool OUT_HL>
__global__ __launch_bounds__(256) void gather_k(const int* __restrict__ rowstart,
                                                const int* __restrict__ csr_src,
                                                const float* __restrict__ dinv,
                                                const float* __restrict__ h,
                                                const float* __restrict__ bias,
                                                float* __restrict__ out,
                                                unsigned int* __restrict__ outHL) {
  const int v = (blockIdx.x * 256 + threadIdx.x) >> 6;
  if (v >= N_NODES) return;
  const int lane = threadIdx.x & 63;
  constexpr int LPE = C / 64;  // 2
  const int rs = rowstart[v];
  const int re = rowstart[v + 1];
  const float dv = dinv[v];

  float a0 = 0.0f, a1 = 0.0f;

  int e = rs;
  for (; e + 3 < re; e += 4) {
    const int s0 = csr_src[e];
    const int s1 = csr_src[e + 1];
    const int s2 = csr_src[e + 2];
    const int s3 = csr_src[e + 3];
    const float n0 = dv * dinv[s0];
    const float n1 = dv * dinv[s1];
    const float n2 = dv * dinv[s2];
    const float n3 = dv * dinv[s3];
    const float2 r0 = *(const float2*)(h + (long)s0 * C + lane * LPE);
    const float2 r1 = *(const float2*)(h + (long)s1 * C + lane * LPE);
    const float2 r2 = *(const float2*)(h + (long)s2 * C + lane * LPE);
    const float2 r3 = *(const float2*)(h + (long)s3 * C + lane * LPE);
    a0 += n0 * r0.x + n1 * r1.x + n2 * r2.x + n3 * r3.x;
    a1 += n0 * r0.y + n1 * r1.y + n2 * r2.y + n3 * r3.y;
  }
  for (; e < re; ++e) {
    const int s0 = csr_src[e];
    const float n0 = dv * dinv[s0];
    const float2 r0 = *(const float2*)(h + (long)s0 * C + lane * LPE);
    a0 += n0 * r0.x;
    a1 += n0 * r0.y;
  }

  const float s2 = dv * dv;
  const float2 hv = *(const float2*)(h + (long)v * C + lane * LPE);
  float2 o = {s2 * hv.x + a0, s2 * hv.y + a1};
  if (HAS_BIAS) {
    const float2 bv = *(const float2*)(bias + lane * LPE);
    o.x += bv.x;
    o.y += bv.y;
  }
  if (OUT_HL) {
    uint2 u = {packHL(o.x), packHL(o.y)};
    *(uint2*)(outHL + (long)v * C + lane * LPE) = u;
  } else {
    *(float2*)(out + (long)v * C + lane * LPE) = o;
  }
}

// ---------------------------------------------------------------------------
extern "C" void kernel_launch(void* const* d_in, const int* in_sizes, int n_in,
                              void* d_out, int out_size, void* d_ws, size_t ws_size,
                              hipStream_t stream) {
  (void)in_sizes; (void)n_in; (void)out_size; (void)ws_size;

  const float* x  = (const float*)d_in[0];
  const int*   ei = (const int*)d_in[1];
  const float* W1 = (const float*)d_in[2];
  const float* b1 = (const float*)d_in[3];
  const float* W2 = (const float*)d_in[4];
  const float* b2 = (const float*)d_in[5];
  float* out = (float*)d_out;

  // Workspace layout (bytes):
  char* ws = (char*)d_ws;
  int*   src      = (int*)(ws + 0);            //  3.2 MB
  int*   dst      = (int*)(ws + 3200000);      //  3.2 MB
  int*   csr_src  = (int*)(ws + 6400000);      //  3.2 MB
  int*   deg      = (int*)(ws + 9600000);      //  0.2 MB
  int*   rowstart = (int*)(ws + 9800000);      //  0.2 MB (N+1)
  int*   cursor   = (int*)(ws + 10000016);     //  0.2 MB
  float* dinv     = (float*)(ws + 10200016);   //  0.2 MB
  int*   bsum     = (int*)(ws + 10400016);
  int*   boff     = (int*)(ws + 10401040);
  unsigned int* w1hl   = (unsigned int*)(ws + 10500000);  // 131 KB
  unsigned int* w2hl   = (unsigned int*)(ws + 10700000);  // 131 KB
  unsigned int* aggxHL = (unsigned int*)(ws + 11000000);  // 25.6 MB
  float*        h2     = (float*)(ws + 11000000);         // alias (aggx dead)
  unsigned int* h1hl   = (unsigned int*)(ws + 40000000);  // 51.2 MB

  const int EB   = (N_EDGES + 255) / 256;  // 3125
  const int GB   = (N_NODES + 3) / 4;      // gather: 1 node/wave
  const int NT64 = (N_NODES + 63) / 64;    // 782 node-tiles for MFMA GEMM

  // ---- Graph preprocessing: CSR by destination + dinv ----
  deg_zero_k<<<NBLK, 256, 0, stream>>>(deg);
  convert_count_k<<<EB, 256, 0, stream>>>(ei, src, dst, deg);
  bsum_k<<<NBLK, 256, 0, stream>>>(deg, bsum);
  bscan_k<<<1, 256, 0, stream>>>(bsum, boff);
  bfinal_k<<<NBLK, 256, 0, stream>>>(deg, boff, rowstart, cursor, dinv);
  fill_csr_k<<<EB, 256, 0, stream>>>(src, dst, cursor, csr_src);

  // ---- Weight splits (tiny) ----
  split_k<<<(HID_C * IN_C + 255) / 256, 256, 0, stream>>>(W1, w1hl, HID_C * IN_C);
  split_k<<<(OUT_C * HID_C + 255) / 256, 256, 0, stream>>>(W2, w2hl, OUT_C * HID_C);

  // ---- Layer 1: aggx = agg(x) (HL out); h1 = relu(aggx@W1^T + b1) (HL out)
  gather_k<IN_C, false, true><<<GB, 256, 0, stream>>>(
      rowstart, csr_src, dinv, x, nullptr, nullptr, aggxHL);
  gemm_mfma_k<IN_C, HID_C, true><<<dim3(NT64, HID_C / 64), 256, 0, stream>>>(
      aggxHL, w1hl, b1, h1hl, nullptr);

  // ---- Layer 2: h2 = h1@W2^T (fp32 out); out = agg(h2) + b2
  gemm_mfma_k<HID_C, OUT_C, false><<<dim3(NT64, OUT_C / 64), 256, 0, stream>>>(
      h1hl, w2hl, nullptr, nullptr, h2);
  gather_k<OUT_C, true, false><<<GB, 256, 0, stream>>>(
      rowstart, csr_src, dinv, h2, b2, out, nullptr);
}

// Round 13
// 297.137 us; speedup vs baseline: 1.2992x; 1.2158x over previous
//
#include <hip/hip_runtime.h>

#define N_NODES 50000
#define N_EDGES 800000
#define IN_C 128
#define HID_C 256
#define OUT_C 128
#define NBLK 196  // ceil(N_NODES / 256)

typedef __attribute__((ext_vector_type(8))) short short8v;  // 8 bf16
typedef __attribute__((ext_vector_type(4))) float f32x4;

static __device__ __forceinline__ unsigned short f2bf(float f) {
  unsigned int u = __float_as_uint(f);
  unsigned int r = (u + 0x7fffu + ((u >> 16) & 1u)) >> 16;  // RNE
  return (unsigned short)r;
}
static __device__ __forceinline__ float bf2f(unsigned short h) {
  return __uint_as_float(((unsigned int)h) << 16);
}
// HL format: u32 = hi_bf16 | lo_bf16<<16, hi+lo ~= 16 mantissa bits of fp32.
static __device__ __forceinline__ unsigned int packHL(float v) {
  const unsigned short h = f2bf(v);
  const unsigned short l = f2bf(v - bf2f(h));
  return (unsigned int)h | ((unsigned int)l << 16);
}
static __device__ __forceinline__ void unpackHL_g(const unsigned int* __restrict__ p,
                                                  short8v& hi, short8v& lo) {
  const uint4 a = *(const uint4*)p;
  const uint4 b = *(const uint4*)(p + 4);
  union { unsigned int u[4]; short8v s; } H, L;
  H.u[0] = (a.x & 0xffffu) | (a.y << 16);
  H.u[1] = (a.z & 0xffffu) | (a.w << 16);
  H.u[2] = (b.x & 0xffffu) | (b.y << 16);
  H.u[3] = (b.z & 0xffffu) | (b.w << 16);
  L.u[0] = (a.x >> 16) | (a.y & 0xffff0000u);
  L.u[1] = (a.z >> 16) | (a.w & 0xffff0000u);
  L.u[2] = (b.x >> 16) | (b.y & 0xffff0000u);
  L.u[3] = (b.z >> 16) | (b.w & 0xffff0000u);
  hi = H.s;
  lo = L.s;
}

// ---------------------------------------------------------------------------
// Edge conversion (int32/int64 auto-detect) fused with dst-degree histogram.
// ---------------------------------------------------------------------------
__global__ __launch_bounds__(256) void deg_zero_k(int* __restrict__ deg) {
  const int i = blockIdx.x * 256 + threadIdx.x;
  if (i < N_NODES) deg[i] = 0;
}

__global__ __launch_bounds__(256) void convert_count_k(const int* __restrict__ ei,
                                                       int* __restrict__ src,
                                                       int* __restrict__ dst,
                                                       int* __restrict__ deg) {
  __shared__ int s_is64;
  if (threadIdx.x == 0) {
    int nz = 0;
#pragma unroll
    for (int k = 0; k < 64; ++k) nz |= ei[2 * k + 1];
    s_is64 = (nz == 0) ? 1 : 0;
  }
  __syncthreads();
  const int is64 = s_is64;
  const int e = blockIdx.x * 256 + threadIdx.x;
  if (e < N_EDGES) {
    int s, d;
    if (is64) {
      s = ei[2 * e];
      d = ei[2 * (N_EDGES + e)];
    } else {
      s = ei[e];
      d = ei[N_EDGES + e];
    }
    src[e] = s;
    dst[e] = d;
    atomicAdd(&deg[d], 1);
  }
}

// ---------------------------------------------------------------------------
// Parallel 3-phase exclusive scan over deg (bsum / bscan / bfinal+dinv).
// ---------------------------------------------------------------------------
__global__ __launch_bounds__(256) void bsum_k(const int* __restrict__ deg,
                                              int* __restrict__ bsum) {
  const int i = blockIdx.x * 256 + threadIdx.x;
  int v = (i < N_NODES) ? deg[i] : 0;
#pragma unroll
  for (int off = 32; off > 0; off >>= 1) v += __shfl_down(v, off, 64);
  __shared__ int ws[4];
  if ((threadIdx.x & 63) == 0) ws[threadIdx.x >> 6] = v;
  __syncthreads();
  if (threadIdx.x == 0) bsum[blockIdx.x] = ws[0] + ws[1] + ws[2] + ws[3];
}

__global__ __launch_bounds__(256) void bscan_k(const int* __restrict__ bsum,
                                               int* __restrict__ boff) {
  __shared__ int s[256];
  const int t = threadIdx.x;
  const int v = (t < NBLK) ? bsum[t] : 0;
  s[t] = v;
  __syncthreads();
  for (int off = 1; off < 256; off <<= 1) {
    const int tmp = (t >= off) ? s[t - off] : 0;
    __syncthreads();
    s[t] += tmp;
    __syncthreads();
  }
  if (t < NBLK) boff[t] = s[t] - v;
}

__global__ __launch_bounds__(256) void bfinal_k(const int* __restrict__ deg,
                                                const int* __restrict__ boff,
                                                int* __restrict__ rowstart,
                                                int* __restrict__ cursor,
                                                float* __restrict__ dinv) {
  __shared__ int s[256];
  const int t = threadIdx.x;
  const int i = blockIdx.x * 256 + t;
  const int d = (i < N_NODES) ? deg[i] : 0;
  s[t] = d;
  __syncthreads();
  for (int off = 1; off < 256; off <<= 1) {
    const int tmp = (t >= off) ? s[t - off] : 0;
    __syncthreads();
    s[t] += tmp;
    __syncthreads();
  }
  const int run = boff[blockIdx.x] + s[t] - d;
  if (i < N_NODES) {
    rowstart[i] = run;
    cursor[i] = run;
    dinv[i] = rsqrtf((float)d + 1.0f);
    if (i == N_NODES - 1) rowstart[N_NODES] = run + d;
  }
}

__global__ __launch_bounds__(256) void fill_csr_k(const int* __restrict__ src,
                                                  const int* __restrict__ dst,
                                                  int* __restrict__ cursor,
                                                  int* __restrict__ csr_src) {
  const int e = blockIdx.x * 256 + threadIdx.x;
  if (e < N_EDGES) {
    const int pos = atomicAdd(&cursor[dst[e]], 1);
    csr_src[pos] = src[e];
  }
}

// ---------------------------------------------------------------------------
// Weight split: fp32 -> HL u32 (bf16 hi | bf16 lo << 16).
// ---------------------------------------------------------------------------
__global__ __launch_bounds__(256) void split_k(const float* __restrict__ in,
                                               unsigned int* __restrict__ hl,
                                               int n) {
  const int i = blockIdx.x * 256 + threadIdx.x;
  if (i < n) hl[i] = packHL(in[i]);
}

// ---------------------------------------------------------------------------
// LDS-staged MFMA GEMM, bf16-split 3-pass, HL operands, swapped operand order.
// Block: 256 thr = 4 waves. Tile: NT nodes x FULL MTOT (X read exactly once).
// Wave w owns m-range [w*MTOT/4, ...). X-tile staged in LDS (stride K+4 u32
// -> 2-way bank alias only). W frags from L2 (131 KB, hot), hoisted per ks.
// D layout (m89-verified, swapped): row=W-row(m), col=X-row(n); lane's 4 acc
// regs = 4 consecutive m for one n -> uint4/float4 stores.
// ---------------------------------------------------------------------------
template <int K, int MTOT, int NT, bool SPLIT_OUT>
__global__ __launch_bounds__(256) void gemm_mfma_k(
    const unsigned int* __restrict__ XHL, const unsigned int* __restrict__ WHL,
    const float* __restrict__ bias, unsigned int* __restrict__ outHL,
    float* __restrict__ outF) {
  constexpr int MW = MTOT / 4;   // m-width per wave
  constexpr int NMT = MW / 16;   // m sub-tiles per wave
  constexpr int NNT = NT / 16;   // n sub-tiles
  constexpr int NKS = K / 32;    // k steps
  constexpr int KP = K + 4;      // padded LDS row stride (u32)
  __shared__ unsigned int xs[NT * KP];

  const int tid = threadIdx.x;
  const int w = tid >> 6;
  const int l = tid & 63;
  const long nbase = (long)blockIdx.x * NT;

  // ---- Stage X-tile (contiguous NT*K u32 span) into LDS, coalesced uint4 ----
  constexpr int SIT = (NT * K) / (256 * 4);
#pragma unroll
  for (int i = 0; i < SIT; ++i) {
    const int idx = (tid + i * 256) * 4;
    const int row = idx / K, col = idx % K;
    long gr = nbase + row;
    if (gr > N_NODES - 1) gr = N_NODES - 1;  // clamp tail; stores guarded
    const uint4 v = *(const uint4*)(XHL + gr * K + col);
    *(uint4*)(xs + row * KP + col) = v;
  }
  __syncthreads();

  const int m0w = w * MW;
  const int kg = (l >> 4) * 8;
  const int lr = l & 15;

  f32x4 acc[NNT][NMT];
#pragma unroll
  for (int nt = 0; nt < NNT; ++nt)
#pragma unroll
    for (int mt = 0; mt < NMT; ++mt) acc[nt][mt] = {0.0f, 0.0f, 0.0f, 0.0f};

#pragma unroll
  for (int ks = 0; ks < NKS; ++ks) {
    const int ko = ks * 32 + kg;
    // Hoist W fragments for this k-step (L2-resident reads)
    short8v wHi[NMT], wLo[NMT];
#pragma unroll
    for (int mt = 0; mt < NMT; ++mt)
      unpackHL_g(WHL + (long)(m0w + mt * 16 + lr) * K + ko, wHi[mt], wLo[mt]);
#pragma unroll
    for (int nt = 0; nt < NNT; ++nt) {
      short8v xHi, xLo;
      unpackHL_g(xs + (nt * 16 + lr) * KP + ko, xHi, xLo);
#pragma unroll
      for (int mt = 0; mt < NMT; ++mt) {
        acc[nt][mt] =
            __builtin_amdgcn_mfma_f32_16x16x32_bf16(wHi[mt], xHi, acc[nt][mt], 0, 0, 0);
        acc[nt][mt] =
            __builtin_amdgcn_mfma_f32_16x16x32_bf16(wLo[mt], xHi, acc[nt][mt], 0, 0, 0);
        acc[nt][mt] =
            __builtin_amdgcn_mfma_f32_16x16x32_bf16(wHi[mt], xLo, acc[nt][mt], 0, 0, 0);
      }
    }
  }

  // ---- Epilogue: lane holds 4 consecutive m for node n ----
  const int mq0 = (l >> 4) * 4;
#pragma unroll
  for (int nt = 0; nt < NNT; ++nt) {
    const long n = nbase + nt * 16 + lr;
    if (n < N_NODES) {
#pragma unroll
      for (int mt = 0; mt < NMT; ++mt) {
        const int mq = m0w + mt * 16 + mq0;
        if (SPLIT_OUT) {
          const float4 bv = *(const float4*)(bias + mq);
          uint4 o;
          o.x = packHL(fmaxf(acc[nt][mt][0] + bv.x, 0.0f));
          o.y = packHL(fmaxf(acc[nt][mt][1] + bv.y, 0.0f));
          o.z = packHL(fmaxf(acc[nt][mt][2] + bv.z, 0.0f));
          o.w = packHL(fmaxf(acc[nt][mt][3] + bv.w, 0.0f));
          *(uint4*)(outHL + n * MTOT + mq) = o;
        } else {
          const float4 o = {acc[nt][mt][0], acc[nt][mt][1], acc[nt][mt][2],
                            acc[nt][mt][3]};
          *(float4*)(outF + n * MTOT + mq) = o;
        }
      }
    }
  }
}

// ---------------------------------------------------------------------------
// Gather-aggregate (one wave per destination node), C=128 -> 2 floats/lane.
// 4-edge unroll. OUT_HL: write HL u32 pair. Else fp32 (+bias).
// ---------------------------------------------------------------------------
template <int C, bool HAS_BIAS, bool OUT_HL>
__global__ __launch_bounds__(256) void gather_k(const int* __restrict__ rowstart,
                                                const int* __restrict__ csr_src,
                                                const float* __restrict__ dinv,
                                                const float* __restrict__ h,
                                                const float* __restrict__ bias,
                                                float* __restrict__ out,
                                                unsigned int* __restrict__ outHL) {
  const int v = (blockIdx.x * 256 + threadIdx.x) >> 6;
  if (v >= N_NODES) return;
  const int lane = threadIdx.x & 63;
  constexpr int LPE = C / 64;  // 2
  const int rs = rowstart[v];
  const int re = rowstart[v + 1];
  const float dv = dinv[v];

  float a0 = 0.0f, a1 = 0.0f;

  int e = rs;
  for (; e + 3 < re; e += 4) {
    const int s0 = csr_src[e];
    const int s1 = csr_src[e + 1];
    const int s2 = csr_src[e + 2];
    const int s3 = csr_src[e + 3];
    const float n0 = dv * dinv[s0];
    const float n1 = dv * dinv[s1];
    const float n2 = dv * dinv[s2];
    const float n3 = dv * dinv[s3];
    const float2 r0 = *(const float2*)(h + (long)s0 * C + lane * LPE);
    const float2 r1 = *(const float2*)(h + (long)s1 * C + lane * LPE);
    const float2 r2 = *(const float2*)(h + (long)s2 * C + lane * LPE);
    const float2 r3 = *(const float2*)(h + (long)s3 * C + lane * LPE);
    a0 += n0 * r0.x + n1 * r1.x + n2 * r2.x + n3 * r3.x;
    a1 += n0 * r0.y + n1 * r1.y + n2 * r2.y + n3 * r3.y;
  }
  for (; e < re; ++e) {
    const int s0 = csr_src[e];
    const float n0 = dv * dinv[s0];
    const float2 r0 = *(const float2*)(h + (long)s0 * C + lane * LPE);
    a0 += n0 * r0.x;
    a1 += n0 * r0.y;
  }

  const float s2 = dv * dv;
  const float2 hv = *(const float2*)(h + (long)v * C + lane * LPE);
  float2 o = {s2 * hv.x + a0, s2 * hv.y + a1};
  if (HAS_BIAS) {
    const float2 bv = *(const float2*)(bias + lane * LPE);
    o.x += bv.x;
    o.y += bv.y;
  }
  if (OUT_HL) {
    uint2 u = {packHL(o.x), packHL(o.y)};
    *(uint2*)(outHL + (long)v * C + lane * LPE) = u;
  } else {
    *(float2*)(out + (long)v * C + lane * LPE) = o;
  }
}

// ---------------------------------------------------------------------------
extern "C" void kernel_launch(void* const* d_in, const int* in_sizes, int n_in,
                              void* d_out, int out_size, void* d_ws, size_t ws_size,
                              hipStream_t stream) {
  (void)in_sizes; (void)n_in; (void)out_size; (void)ws_size;

  const float* x  = (const float*)d_in[0];
  const int*   ei = (const int*)d_in[1];
  const float* W1 = (const float*)d_in[2];
  const float* b1 = (const float*)d_in[3];
  const float* W2 = (const float*)d_in[4];
  const float* b2 = (const float*)d_in[5];
  float* out = (float*)d_out;

  // Workspace layout (bytes):
  char* ws = (char*)d_ws;
  int*   src      = (int*)(ws + 0);            //  3.2 MB
  int*   dst      = (int*)(ws + 3200000);      //  3.2 MB
  int*   csr_src  = (int*)(ws + 6400000);      //  3.2 MB
  int*   deg      = (int*)(ws + 9600000);      //  0.2 MB
  int*   rowstart = (int*)(ws + 9800000);      //  0.2 MB (N+1)
  int*   cursor   = (int*)(ws + 10000016);     //  0.2 MB
  float* dinv     = (float*)(ws + 10200016);   //  0.2 MB
  int*   bsum     = (int*)(ws + 10400016);
  int*   boff     = (int*)(ws + 10401040);
  unsigned int* w1hl   = (unsigned int*)(ws + 10500000);  // 131 KB
  unsigned int* w2hl   = (unsigned int*)(ws + 10700000);  // 131 KB
  unsigned int* aggxHL = (unsigned int*)(ws + 11000000);  // 25.6 MB
  float*        h2     = (float*)(ws + 11000000);         // alias (aggx dead)
  unsigned int* h1hl   = (unsigned int*)(ws + 40000000);  // 51.2 MB

  const int EB = (N_EDGES + 255) / 256;  // 3125
  const int GB = (N_NODES + 3) / 4;      // gather: 1 node/wave

  // ---- Graph preprocessing: CSR by destination + dinv ----
  deg_zero_k<<<NBLK, 256, 0, stream>>>(deg);
  convert_count_k<<<EB, 256, 0, stream>>>(ei, src, dst, deg);
  bsum_k<<<NBLK, 256, 0, stream>>>(deg, bsum);
  bscan_k<<<1, 256, 0, stream>>>(bsum, boff);
  bfinal_k<<<NBLK, 256, 0, stream>>>(deg, boff, rowstart, cursor, dinv);
  fill_csr_k<<<EB, 256, 0, stream>>>(src, dst, cursor, csr_src);

  // ---- Weight splits (tiny) ----
  split_k<<<(HID_C * IN_C + 255) / 256, 256, 0, stream>>>(W1, w1hl, HID_C * IN_C);
  split_k<<<(OUT_C * HID_C + 255) / 256, 256, 0, stream>>>(W2, w2hl, OUT_C * HID_C);

  // ---- Layer 1: aggx = agg(x) (HL out); h1 = relu(aggx@W1^T + b1) (HL out)
  gather_k<IN_C, false, true><<<GB, 256, 0, stream>>>(
      rowstart, csr_src, dinv, x, nullptr, nullptr, aggxHL);
  gemm_mfma_k<IN_C, HID_C, 64, true><<<(N_NODES + 63) / 64, 256, 0, stream>>>(
      aggxHL, w1hl, b1, h1hl, nullptr);

  // ---- Layer 2: h2 = h1@W2^T (fp32 out); out = agg(h2) + b2
  gemm_mfma_k<HID_C, OUT_C, 32, false><<<(N_NODES + 31) / 32, 256, 0, stream>>>(
      h1hl, w2hl, nullptr, nullptr, h2);
  gather_k<OUT_C, true, false><<<GB, 256, 0, stream>>>(
      rowstart, csr_src, dinv, h2, b2, out, nullptr);
}

// Round 14
// 257.609 us; speedup vs baseline: 1.4985x; 1.1534x over previous
//
#include <hip/hip_runtime.h>

#define N_NODES 50000
#define N_EDGES 800000
#define IN_C 128
#define HID_C 256
#define OUT_C 128
#define NBLK 196  // ceil(N_NODES / 256)

typedef __attribute__((ext_vector_type(8))) short short8v;  // 8 bf16
typedef __attribute__((ext_vector_type(4))) float f32x4;

static __device__ __forceinline__ unsigned short f2bf(float f) {
  unsigned int u = __float_as_uint(f);
  unsigned int r = (u + 0x7fffu + ((u >> 16) & 1u)) >> 16;  // RNE
  return (unsigned short)r;
}
static __device__ __forceinline__ float bf2f(unsigned short h) {
  return __uint_as_float(((unsigned int)h) << 16);
}
// HL format: u32 = hi_bf16 | lo_bf16<<16, hi+lo ~= 16 mantissa bits of fp32.
static __device__ __forceinline__ unsigned int packHL(float v) {
  const unsigned short h = f2bf(v);
  const unsigned short l = f2bf(v - bf2f(h));
  return (unsigned int)h | ((unsigned int)l << 16);
}
// bf16 pair packing: u32 = bf(a) | bf(b)<<16
static __device__ __forceinline__ unsigned int packBF2(float a, float b) {
  return (unsigned int)f2bf(a) | ((unsigned int)f2bf(b) << 16);
}
static __device__ __forceinline__ void unpackHL_g(const unsigned int* __restrict__ p,
                                                  short8v& hi, short8v& lo) {
  const uint4 a = *(const uint4*)p;
  const uint4 b = *(const uint4*)(p + 4);
  union { unsigned int u[4]; short8v s; } H, L;
  H.u[0] = (a.x & 0xffffu) | (a.y << 16);
  H.u[1] = (a.z & 0xffffu) | (a.w << 16);
  H.u[2] = (b.x & 0xffffu) | (b.y << 16);
  H.u[3] = (b.z & 0xffffu) | (b.w << 16);
  L.u[0] = (a.x >> 16) | (a.y & 0xffff0000u);
  L.u[1] = (a.z >> 16) | (a.w & 0xffff0000u);
  L.u[2] = (b.x >> 16) | (b.y & 0xffff0000u);
  L.u[3] = (b.z >> 16) | (b.w & 0xffff0000u);
  hi = H.s;
  lo = L.s;
}

// ---------------------------------------------------------------------------
// Edge conversion (int32/int64 auto-detect) fused with dst-degree histogram.
// ---------------------------------------------------------------------------
__global__ __launch_bounds__(256) void deg_zero_k(int* __restrict__ deg) {
  const int i = blockIdx.x * 256 + threadIdx.x;
  if (i < N_NODES) deg[i] = 0;
}

__global__ __launch_bounds__(256) void convert_count_k(const int* __restrict__ ei,
                                                       int* __restrict__ src,
                                                       int* __restrict__ dst,
                                                       int* __restrict__ deg) {
  __shared__ int s_is64;
  if (threadIdx.x == 0) {
    int nz = 0;
#pragma unroll
    for (int k = 0; k < 64; ++k) nz |= ei[2 * k + 1];
    s_is64 = (nz == 0) ? 1 : 0;
  }
  __syncthreads();
  const int is64 = s_is64;
  const int e = blockIdx.x * 256 + threadIdx.x;
  if (e < N_EDGES) {
    int s, d;
    if (is64) {
      s = ei[2 * e];
      d = ei[2 * (N_EDGES + e)];
    } else {
      s = ei[e];
      d = ei[N_EDGES + e];
    }
    src[e] = s;
    dst[e] = d;
    atomicAdd(&deg[d], 1);
  }
}

// ---------------------------------------------------------------------------
// Parallel 3-phase exclusive scan over deg (bsum / bscan / bfinal+dinv).
// ---------------------------------------------------------------------------
__global__ __launch_bounds__(256) void bsum_k(const int* __restrict__ deg,
                                              int* __restrict__ bsum) {
  const int i = blockIdx.x * 256 + threadIdx.x;
  int v = (i < N_NODES) ? deg[i] : 0;
#pragma unroll
  for (int off = 32; off > 0; off >>= 1) v += __shfl_down(v, off, 64);
  __shared__ int ws[4];
  if ((threadIdx.x & 63) == 0) ws[threadIdx.x >> 6] = v;
  __syncthreads();
  if (threadIdx.x == 0) bsum[blockIdx.x] = ws[0] + ws[1] + ws[2] + ws[3];
}

__global__ __launch_bounds__(256) void bscan_k(const int* __restrict__ bsum,
                                               int* __restrict__ boff) {
  __shared__ int s[256];
  const int t = threadIdx.x;
  const int v = (t < NBLK) ? bsum[t] : 0;
  s[t] = v;
  __syncthreads();
  for (int off = 1; off < 256; off <<= 1) {
    const int tmp = (t >= off) ? s[t - off] : 0;
    __syncthreads();
    s[t] += tmp;
    __syncthreads();
  }
  if (t < NBLK) boff[t] = s[t] - v;
}

__global__ __launch_bounds__(256) void bfinal_k(const int* __restrict__ deg,
                                                const int* __restrict__ boff,
                                                int* __restrict__ rowstart,
                                                int* __restrict__ cursor,
                                                float* __restrict__ dinv) {
  __shared__ int s[256];
  const int t = threadIdx.x;
  const int i = blockIdx.x * 256 + t;
  const int d = (i < N_NODES) ? deg[i] : 0;
  s[t] = d;
  __syncthreads();
  for (int off = 1; off < 256; off <<= 1) {
    const int tmp = (t >= off) ? s[t - off] : 0;
    __syncthreads();
    s[t] += tmp;
    __syncthreads();
  }
  const int run = boff[blockIdx.x] + s[t] - d;
  if (i < N_NODES) {
    rowstart[i] = run;
    cursor[i] = run;
    dinv[i] = rsqrtf((float)d + 1.0f);
    if (i == N_NODES - 1) rowstart[N_NODES] = run + d;
  }
}

__global__ __launch_bounds__(256) void fill_csr_k(const int* __restrict__ src,
                                                  const int* __restrict__ dst,
                                                  int* __restrict__ cursor,
                                                  int* __restrict__ csr_src) {
  const int e = blockIdx.x * 256 + threadIdx.x;
  if (e < N_EDGES) {
    const int pos = atomicAdd(&cursor[dst[e]], 1);
    csr_src[pos] = src[e];
  }
}

// ---------------------------------------------------------------------------
// Weight split: fp32 -> HL u32. x convert: fp32 -> packed bf16 pairs.
// ---------------------------------------------------------------------------
__global__ __launch_bounds__(256) void split_k(const float* __restrict__ in,
                                               unsigned int* __restrict__ hl,
                                               int n) {
  const int i = blockIdx.x * 256 + threadIdx.x;
  if (i < n) hl[i] = packHL(in[i]);
}

__global__ __launch_bounds__(256) void f2bf2_k(const float* __restrict__ in,
                                               unsigned int* __restrict__ outp,
                                               int n4) {  // n4 = n/4
  const int i = blockIdx.x * 256 + threadIdx.x;
  if (i < n4) {
    const float4 f = *(const float4*)(in + i * 4);
    uint2 u = {packBF2(f.x, f.y), packBF2(f.z, f.w)};
    *(uint2*)(outp + i * 2) = u;
  }
}

// ---------------------------------------------------------------------------
// LDS-staged MFMA GEMM, bf16-split 3-pass, HL operands, swapped operand order.
// OUTMODE 0: bias+relu, HL u32x4 store (GEMM1). 1: packed-bf16 uint2 store.
// ---------------------------------------------------------------------------
template <int K, int MTOT, int NT, int OUTMODE>
__global__ __launch_bounds__(256) void gemm_mfma_k(
    const unsigned int* __restrict__ XHL, const unsigned int* __restrict__ WHL,
    const float* __restrict__ bias, unsigned int* __restrict__ outHL,
    unsigned int* __restrict__ outBF) {
  constexpr int MW = MTOT / 4;
  constexpr int NMT = MW / 16;
  constexpr int NNT = NT / 16;
  constexpr int NKS = K / 32;
  constexpr int KP = K + 4;
  __shared__ unsigned int xs[NT * KP];

  const int tid = threadIdx.x;
  const int w = tid >> 6;
  const int l = tid & 63;
  const long nbase = (long)blockIdx.x * NT;

  constexpr int SIT = (NT * K) / (256 * 4);
#pragma unroll
  for (int i = 0; i < SIT; ++i) {
    const int idx = (tid + i * 256) * 4;
    const int row = idx / K, col = idx % K;
    long gr = nbase + row;
    if (gr > N_NODES - 1) gr = N_NODES - 1;
    const uint4 v = *(const uint4*)(XHL + gr * K + col);
    *(uint4*)(xs + row * KP + col) = v;
  }
  __syncthreads();

  const int m0w = w * MW;
  const int kg = (l >> 4) * 8;
  const int lr = l & 15;

  f32x4 acc[NNT][NMT];
#pragma unroll
  for (int nt = 0; nt < NNT; ++nt)
#pragma unroll
    for (int mt = 0; mt < NMT; ++mt) acc[nt][mt] = {0.0f, 0.0f, 0.0f, 0.0f};

#pragma unroll
  for (int ks = 0; ks < NKS; ++ks) {
    const int ko = ks * 32 + kg;
    short8v wHi[NMT], wLo[NMT];
#pragma unroll
    for (int mt = 0; mt < NMT; ++mt)
      unpackHL_g(WHL + (long)(m0w + mt * 16 + lr) * K + ko, wHi[mt], wLo[mt]);
#pragma unroll
    for (int nt = 0; nt < NNT; ++nt) {
      short8v xHi, xLo;
      unpackHL_g(xs + (nt * 16 + lr) * KP + ko, xHi, xLo);
#pragma unroll
      for (int mt = 0; mt < NMT; ++mt) {
        acc[nt][mt] =
            __builtin_amdgcn_mfma_f32_16x16x32_bf16(wHi[mt], xHi, acc[nt][mt], 0, 0, 0);
        acc[nt][mt] =
            __builtin_amdgcn_mfma_f32_16x16x32_bf16(wLo[mt], xHi, acc[nt][mt], 0, 0, 0);
        acc[nt][mt] =
            __builtin_amdgcn_mfma_f32_16x16x32_bf16(wHi[mt], xLo, acc[nt][mt], 0, 0, 0);
      }
    }
  }

  const int mq0 = (l >> 4) * 4;
#pragma unroll
  for (int nt = 0; nt < NNT; ++nt) {
    const long n = nbase + nt * 16 + lr;
    if (n < N_NODES) {
#pragma unroll
      for (int mt = 0; mt < NMT; ++mt) {
        const int mq = m0w + mt * 16 + mq0;
        if (OUTMODE == 0) {
          const float4 bv = *(const float4*)(bias + mq);
          uint4 o;
          o.x = packHL(fmaxf(acc[nt][mt][0] + bv.x, 0.0f));
          o.y = packHL(fmaxf(acc[nt][mt][1] + bv.y, 0.0f));
          o.z = packHL(fmaxf(acc[nt][mt][2] + bv.z, 0.0f));
          o.w = packHL(fmaxf(acc[nt][mt][3] + bv.w, 0.0f));
          *(uint4*)(outHL + n * MTOT + mq) = o;
        } else {
          uint2 o = {packBF2(acc[nt][mt][0], acc[nt][mt][1]),
                     packBF2(acc[nt][mt][2], acc[nt][mt][3])};
          *(uint2*)(outBF + n * (MTOT / 2) + mq / 2) = o;
        }
      }
    }
  }
}

// ---------------------------------------------------------------------------
// Gather-aggregate (one wave per destination node) over PACKED-BF16 rows.
// Lane reads 1 u32 = 2 channels per row. 4-edge unroll.
// OUT_HL: write HL u32 pair (feeds GEMM1). Else fp32 (+bias) final output.
// ---------------------------------------------------------------------------
template <int C, bool HAS_BIAS, bool OUT_HL>
__global__ __launch_bounds__(256) void gather_k(const int* __restrict__ rowstart,
                                                const int* __restrict__ csr_src,
                                                const float* __restrict__ dinv,
                                                const unsigned int* __restrict__ hbf,
                                                const float* __restrict__ bias,
                                                float* __restrict__ out,
                                                unsigned int* __restrict__ outHL) {
  const int v = (blockIdx.x * 256 + threadIdx.x) >> 6;
  if (v >= N_NODES) return;
  const int lane = threadIdx.x & 63;
  constexpr int CW = C / 2;  // u32 words per row
  const int rs = rowstart[v];
  const int re = rowstart[v + 1];
  const float dv = dinv[v];

  float a0 = 0.0f, a1 = 0.0f;

  int e = rs;
  for (; e + 3 < re; e += 4) {
    const int s0 = csr_src[e];
    const int s1 = csr_src[e + 1];
    const int s2 = csr_src[e + 2];
    const int s3 = csr_src[e + 3];
    const float n0 = dv * dinv[s0];
    const float n1 = dv * dinv[s1];
    const float n2 = dv * dinv[s2];
    const float n3 = dv * dinv[s3];
    const unsigned int r0 = hbf[(long)s0 * CW + lane];
    const unsigned int r1 = hbf[(long)s1 * CW + lane];
    const unsigned int r2 = hbf[(long)s2 * CW + lane];
    const unsigned int r3 = hbf[(long)s3 * CW + lane];
    a0 += n0 * bf2f((unsigned short)r0) + n1 * bf2f((unsigned short)r1) +
          n2 * bf2f((unsigned short)r2) + n3 * bf2f((unsigned short)r3);
    a1 += n0 * bf2f((unsigned short)(r0 >> 16)) + n1 * bf2f((unsigned short)(r1 >> 16)) +
          n2 * bf2f((unsigned short)(r2 >> 16)) + n3 * bf2f((unsigned short)(r3 >> 16));
  }
  for (; e < re; ++e) {
    const int s0 = csr_src[e];
    const float n0 = dv * dinv[s0];
    const unsigned int r0 = hbf[(long)s0 * CW + lane];
    a0 += n0 * bf2f((unsigned short)r0);
    a1 += n0 * bf2f((unsigned short)(r0 >> 16));
  }

  const float s2 = dv * dv;
  const unsigned int hv = hbf[(long)v * CW + lane];
  float o0 = s2 * bf2f((unsigned short)hv) + a0;
  float o1 = s2 * bf2f((unsigned short)(hv >> 16)) + a1;
  if (HAS_BIAS) {
    const float2 bv = *(const float2*)(bias + lane * 2);
    o0 += bv.x;
    o1 += bv.y;
  }
  if (OUT_HL) {
    uint2 u = {packHL(o0), packHL(o1)};
    *(uint2*)(outHL + (long)v * C + lane * 2) = u;
  } else {
    const float2 o = {o0, o1};
    *(float2*)(out + (long)v * C + lane * 2) = o;
  }
}

// ---------------------------------------------------------------------------
extern "C" void kernel_launch(void* const* d_in, const int* in_sizes, int n_in,
                              void* d_out, int out_size, void* d_ws, size_t ws_size,
                              hipStream_t stream) {
  (void)in_sizes; (void)n_in; (void)out_size; (void)ws_size;

  const float* x  = (const float*)d_in[0];
  const int*   ei = (const int*)d_in[1];
  const float* W1 = (const float*)d_in[2];
  const float* b1 = (const float*)d_in[3];
  const float* W2 = (const float*)d_in[4];
  const float* b2 = (const float*)d_in[5];
  float* out = (float*)d_out;

  // Workspace layout (bytes):
  char* ws = (char*)d_ws;
  int*   src      = (int*)(ws + 0);            //  3.2 MB
  int*   dst      = (int*)(ws + 3200000);      //  3.2 MB
  int*   csr_src  = (int*)(ws + 6400000);      //  3.2 MB
  int*   deg      = (int*)(ws + 9600000);      //  0.2 MB
  int*   rowstart = (int*)(ws + 9800000);      //  0.2 MB (N+1)
  int*   cursor   = (int*)(ws + 10000016);     //  0.2 MB
  float* dinv     = (float*)(ws + 10200016);   //  0.2 MB
  int*   bsum     = (int*)(ws + 10400016);
  int*   boff     = (int*)(ws + 10401040);
  unsigned int* w1hl   = (unsigned int*)(ws + 10500000);  // 131 KB
  unsigned int* w2hl   = (unsigned int*)(ws + 10700000);  // 131 KB
  unsigned int* aggxHL = (unsigned int*)(ws + 11000000);  // 25.6 MB
  unsigned int* h2bf   = (unsigned int*)(ws + 11000000);  // 12.8 MB alias (aggx dead)
  unsigned int* h1hl   = (unsigned int*)(ws + 40000000);  // 51.2 MB
  unsigned int* xbf    = (unsigned int*)(ws + 91200000);  // 12.8 MB

  const int EB = (N_EDGES + 255) / 256;  // 3125
  const int GB = (N_NODES + 3) / 4;      // gather: 1 node/wave

  // ---- Graph preprocessing: CSR by destination + dinv ----
  deg_zero_k<<<NBLK, 256, 0, stream>>>(deg);
  convert_count_k<<<EB, 256, 0, stream>>>(ei, src, dst, deg);
  bsum_k<<<NBLK, 256, 0, stream>>>(deg, bsum);
  bscan_k<<<1, 256, 0, stream>>>(bsum, boff);
  bfinal_k<<<NBLK, 256, 0, stream>>>(deg, boff, rowstart, cursor, dinv);
  fill_csr_k<<<EB, 256, 0, stream>>>(src, dst, cursor, csr_src);

  // ---- Operand conversions ----
  split_k<<<(HID_C * IN_C + 255) / 256, 256, 0, stream>>>(W1, w1hl, HID_C * IN_C);
  split_k<<<(OUT_C * HID_C + 255) / 256, 256, 0, stream>>>(W2, w2hl, OUT_C * HID_C);
  f2bf2_k<<<(N_NODES * IN_C / 4 + 255) / 256, 256, 0, stream>>>(
      x, xbf, N_NODES * IN_C / 4);

  // ---- Layer 1: aggx = agg(x_bf16) (HL out); h1 = relu(aggx@W1^T+b1) (HL out)
  gather_k<IN_C, false, true><<<GB, 256, 0, stream>>>(
      rowstart, csr_src, dinv, xbf, nullptr, nullptr, aggxHL);
  gemm_mfma_k<IN_C, HID_C, 64, 0><<<(N_NODES + 63) / 64, 256, 0, stream>>>(
      aggxHL, w1hl, b1, h1hl, nullptr);

  // ---- Layer 2: h2 = h1@W2^T (packed bf16 out); out = agg(h2_bf16) + b2
  gemm_mfma_k<HID_C, OUT_C, 32, 1><<<(N_NODES + 31) / 32, 256, 0, stream>>>(
      h1hl, w2hl, nullptr, nullptr, h2bf);
  gather_k<OUT_C, true, false><<<GB, 256, 0, stream>>>(
      rowstart, csr_src, dinv, h2bf, b2, out, nullptr);
}

// Round 15
// 227.788 us; speedup vs baseline: 1.6947x; 1.1309x over previous
//
#include <hip/hip_runtime.h>

#define N_NODES 50000
#define N_EDGES 800000
#define IN_C 128
#define HID_C 256
#define OUT_C 128
#define NBLK 196   // ceil(N_NODES / 256)
#define NPART 8    // XCD count; partition width = N_NODES/8 = 6250

typedef __attribute__((ext_vector_type(8))) short short8v;  // 8 bf16
typedef __attribute__((ext_vector_type(4))) float f32x4;

static __device__ __forceinline__ unsigned short f2bf(float f) {
  unsigned int u = __float_as_uint(f);
  unsigned int r = (u + 0x7fffu + ((u >> 16) & 1u)) >> 16;  // RNE
  return (unsigned short)r;
}
static __device__ __forceinline__ float bf2f(unsigned short h) {
  return __uint_as_float(((unsigned int)h) << 16);
}
// HL format: u32 = hi_bf16 | lo_bf16<<16, hi+lo ~= 16 mantissa bits of fp32.
static __device__ __forceinline__ unsigned int packHL(float v) {
  const unsigned short h = f2bf(v);
  const unsigned short l = f2bf(v - bf2f(h));
  return (unsigned int)h | ((unsigned int)l << 16);
}
// bf16 pair packing: u32 = bf(a) | bf(b)<<16
static __device__ __forceinline__ unsigned int packBF2(float a, float b) {
  return (unsigned int)f2bf(a) | ((unsigned int)f2bf(b) << 16);
}
static __device__ __forceinline__ void unpackHL_g(const unsigned int* __restrict__ p,
                                                  short8v& hi, short8v& lo) {
  const uint4 a = *(const uint4*)p;
  const uint4 b = *(const uint4*)(p + 4);
  union { unsigned int u[4]; short8v s; } H, L;
  H.u[0] = (a.x & 0xffffu) | (a.y << 16);
  H.u[1] = (a.z & 0xffffu) | (a.w << 16);
  H.u[2] = (b.x & 0xffffu) | (b.y << 16);
  H.u[3] = (b.z & 0xffffu) | (b.w << 16);
  L.u[0] = (a.x >> 16) | (a.y & 0xffff0000u);
  L.u[1] = (a.z >> 16) | (a.w & 0xffff0000u);
  L.u[2] = (b.x >> 16) | (b.y & 0xffff0000u);
  L.u[3] = (b.z >> 16) | (b.w & 0xffff0000u);
  hi = H.s;
  lo = L.s;
}

// ---------------------------------------------------------------------------
// Edge conversion (int32/int64 auto-detect) + dst-degree histogram.
// The atomicAdd RETURN VALUE is the edge's rank within its dst-bucket; pack
// edata[e] = { dst | rank<<16 , src } (dst<50000, rank<65536 for this graph).
// ---------------------------------------------------------------------------
__global__ __launch_bounds__(256) void deg_zero_k(int* __restrict__ deg) {
  const int i = blockIdx.x * 256 + threadIdx.x;
  if (i < N_NODES) deg[i] = 0;
}

__global__ __launch_bounds__(256) void convert_count_k(const int* __restrict__ ei,
                                                       uint2* __restrict__ edata,
                                                       int* __restrict__ deg) {
  __shared__ int s_is64;
  if (threadIdx.x == 0) {
    int nz = 0;
#pragma unroll
    for (int k = 0; k < 64; ++k) nz |= ei[2 * k + 1];
    s_is64 = (nz == 0) ? 1 : 0;
  }
  __syncthreads();
  const int is64 = s_is64;
  const int e = blockIdx.x * 256 + threadIdx.x;
  if (e < N_EDGES) {
    int s, d;
    if (is64) {
      s = ei[2 * e];
      d = ei[2 * (N_EDGES + e)];
    } else {
      s = ei[e];
      d = ei[N_EDGES + e];
    }
    const int r = atomicAdd(&deg[d], 1);  // rank within bucket
    const uint2 t = {(unsigned int)d | ((unsigned int)r << 16), (unsigned int)s};
    edata[e] = t;
  }
}

// ---------------------------------------------------------------------------
// Parallel 3-phase exclusive scan over deg (bsum / bscan / bfinal+dinv).
// ---------------------------------------------------------------------------
__global__ __launch_bounds__(256) void bsum_k(const int* __restrict__ deg,
                                              int* __restrict__ bsum) {
  const int i = blockIdx.x * 256 + threadIdx.x;
  int v = (i < N_NODES) ? deg[i] : 0;
#pragma unroll
  for (int off = 32; off > 0; off >>= 1) v += __shfl_down(v, off, 64);
  __shared__ int ws[4];
  if ((threadIdx.x & 63) == 0) ws[threadIdx.x >> 6] = v;
  __syncthreads();
  if (threadIdx.x == 0) bsum[blockIdx.x] = ws[0] + ws[1] + ws[2] + ws[3];
}

__global__ __launch_bounds__(256) void bscan_k(const int* __restrict__ bsum,
                                               int* __restrict__ boff) {
  __shared__ int s[256];
  const int t = threadIdx.x;
  const int v = (t < NBLK) ? bsum[t] : 0;
  s[t] = v;
  __syncthreads();
  for (int off = 1; off < 256; off <<= 1) {
    const int tmp = (t >= off) ? s[t - off] : 0;
    __syncthreads();
    s[t] += tmp;
    __syncthreads();
  }
  if (t < NBLK) boff[t] = s[t] - v;
}

__global__ __launch_bounds__(256) void bfinal_k(const int* __restrict__ deg,
                                                const int* __restrict__ boff,
                                                int* __restrict__ rowstart,
                                                float* __restrict__ dinv) {
  __shared__ int s[256];
  const int t = threadIdx.x;
  const int i = blockIdx.x * 256 + t;
  const int d = (i < N_NODES) ? deg[i] : 0;
  s[t] = d;
  __syncthreads();
  for (int off = 1; off < 256; off <<= 1) {
    const int tmp = (t >= off) ? s[t - off] : 0;
    __syncthreads();
    s[t] += tmp;
    __syncthreads();
  }
  const int run = boff[blockIdx.x] + s[t] - d;
  if (i < N_NODES) {
    rowstart[i] = run;
    dinv[i] = rsqrtf((float)d + 1.0f);
    if (i == N_NODES - 1) rowstart[N_NODES] = run + d;
  }
}

// ---------------------------------------------------------------------------
// XCD-partitioned, atomic-free CSR fill. Block bx: partition p = bx&7
// (round-robin workgroup->XCD dispatch => one partition per XCD), edge chunk
// bx>>3. Only edges with dst/6250 == p are written => each dst-bucket's
// contiguous csr slots are written by ONE XCD => lines coalesce in its L2.
// ---------------------------------------------------------------------------
__global__ __launch_bounds__(256) void fill_csr_part_k(const uint2* __restrict__ edata,
                                                       const int* __restrict__ rowstart,
                                                       int* __restrict__ csr_src) {
  const int p = blockIdx.x & 7;
  const int e = (blockIdx.x >> 3) * 256 + threadIdx.x;
  if (e < N_EDGES) {
    const uint2 t = edata[e];
    const int d = t.x & 0xffff;
    const int r = t.x >> 16;
    if (d / 6250 == p) csr_src[rowstart[d] + r] = (int)t.y;
  }
}

// ---------------------------------------------------------------------------
// Weight split: fp32 -> HL u32. x convert: fp32 -> packed bf16 pairs.
// ---------------------------------------------------------------------------
__global__ __launch_bounds__(256) void split_k(const float* __restrict__ in,
                                               unsigned int* __restrict__ hl,
                                               int n) {
  const int i = blockIdx.x * 256 + threadIdx.x;
  if (i < n) hl[i] = packHL(in[i]);
}

__global__ __launch_bounds__(256) void f2bf2_k(const float* __restrict__ in,
                                               unsigned int* __restrict__ outp,
                                               int n4) {  // n4 = n/4
  const int i = blockIdx.x * 256 + threadIdx.x;
  if (i < n4) {
    const float4 f = *(const float4*)(in + i * 4);
    uint2 u = {packBF2(f.x, f.y), packBF2(f.z, f.w)};
    *(uint2*)(outp + i * 2) = u;
  }
}

// ---------------------------------------------------------------------------
// LDS-staged MFMA GEMM, bf16-split 3-pass, HL operands, swapped operand order.
// OUTMODE 0: bias+relu, HL u32x4 store (GEMM1). 1: packed-bf16 uint2 store.
// ---------------------------------------------------------------------------
template <int K, int MTOT, int NT, int OUTMODE>
__global__ __launch_bounds__(256) void gemm_mfma_k(
    const unsigned int* __restrict__ XHL, const unsigned int* __restrict__ WHL,
    const float* __restrict__ bias, unsigned int* __restrict__ outHL,
    unsigned int* __restrict__ outBF) {
  constexpr int MW = MTOT / 4;
  constexpr int NMT = MW / 16;
  constexpr int NNT = NT / 16;
  constexpr int NKS = K / 32;
  constexpr int KP = K + 4;
  __shared__ unsigned int xs[NT * KP];

  const int tid = threadIdx.x;
  const int w = tid >> 6;
  const int l = tid & 63;
  const long nbase = (long)blockIdx.x * NT;

  constexpr int SIT = (NT * K) / (256 * 4);
#pragma unroll
  for (int i = 0; i < SIT; ++i) {
    const int idx = (tid + i * 256) * 4;
    const int row = idx / K, col = idx % K;
    long gr = nbase + row;
    if (gr > N_NODES - 1) gr = N_NODES - 1;
    const uint4 v = *(const uint4*)(XHL + gr * K + col);
    *(uint4*)(xs + row * KP + col) = v;
  }
  __syncthreads();

  const int m0w = w * MW;
  const int kg = (l >> 4) * 8;
  const int lr = l & 15;

  f32x4 acc[NNT][NMT];
#pragma unroll
  for (int nt = 0; nt < NNT; ++nt)
#pragma unroll
    for (int mt = 0; mt < NMT; ++mt) acc[nt][mt] = {0.0f, 0.0f, 0.0f, 0.0f};

#pragma unroll
  for (int ks = 0; ks < NKS; ++ks) {
    const int ko = ks * 32 + kg;
    short8v wHi[NMT], wLo[NMT];
#pragma unroll
    for (int mt = 0; mt < NMT; ++mt)
      unpackHL_g(WHL + (long)(m0w + mt * 16 + lr) * K + ko, wHi[mt], wLo[mt]);
#pragma unroll
    for (int nt = 0; nt < NNT; ++nt) {
      short8v xHi, xLo;
      unpackHL_g(xs + (nt * 16 + lr) * KP + ko, xHi, xLo);
#pragma unroll
      for (int mt = 0; mt < NMT; ++mt) {
        acc[nt][mt] =
            __builtin_amdgcn_mfma_f32_16x16x32_bf16(wHi[mt], xHi, acc[nt][mt], 0, 0, 0);
        acc[nt][mt] =
            __builtin_amdgcn_mfma_f32_16x16x32_bf16(wLo[mt], xHi, acc[nt][mt], 0, 0, 0);
        acc[nt][mt] =
            __builtin_amdgcn_mfma_f32_16x16x32_bf16(wHi[mt], xLo, acc[nt][mt], 0, 0, 0);
      }
    }
  }

  const int mq0 = (l >> 4) * 4;
#pragma unroll
  for (int nt = 0; nt < NNT; ++nt) {
    const long n = nbase + nt * 16 + lr;
    if (n < N_NODES) {
#pragma unroll
      for (int mt = 0; mt < NMT; ++mt) {
        const int mq = m0w + mt * 16 + mq0;
        if (OUTMODE == 0) {
          const float4 bv = *(const float4*)(bias + mq);
          uint4 o;
          o.x = packHL(fmaxf(acc[nt][mt][0] + bv.x, 0.0f));
          o.y = packHL(fmaxf(acc[nt][mt][1] + bv.y, 0.0f));
          o.z = packHL(fmaxf(acc[nt][mt][2] + bv.z, 0.0f));
          o.w = packHL(fmaxf(acc[nt][mt][3] + bv.w, 0.0f));
          *(uint4*)(outHL + n * MTOT + mq) = o;
        } else {
          uint2 o = {packBF2(acc[nt][mt][0], acc[nt][mt][1]),
                     packBF2(acc[nt][mt][2], acc[nt][mt][3])};
          *(uint2*)(outBF + n * (MTOT / 2) + mq / 2) = o;
        }
      }
    }
  }
}

// ---------------------------------------------------------------------------
// Gather-aggregate (one wave per destination node) over PACKED-BF16 rows.
// Lane reads 1 u32 = 2 channels per row. 4-edge unroll.
// OUT_HL: write HL u32 pair (feeds GEMM1). Else fp32 (+bias) final output.
// ---------------------------------------------------------------------------
template <int C, bool HAS_BIAS, bool OUT_HL>
__global__ __launch_bounds__(256) void gather_k(const int* __restrict__ rowstart,
                                                const int* __restrict__ csr_src,
                                                const float* __restrict__ dinv,
                                                const unsigned int* __restrict__ hbf,
                                                const float* __restrict__ bias,
                                                float* __restrict__ out,
                                                unsigned int* __restrict__ outHL) {
  const int v = (blockIdx.x * 256 + threadIdx.x) >> 6;
  if (v >= N_NODES) return;
  const int lane = threadIdx.x & 63;
  constexpr int CW = C / 2;  // u32 words per row
  const int rs = rowstart[v];
  const int re = rowstart[v + 1];
  const float dv = dinv[v];

  float a0 = 0.0f, a1 = 0.0f;

  int e = rs;
  for (; e + 3 < re; e += 4) {
    const int s0 = csr_src[e];
    const int s1 = csr_src[e + 1];
    const int s2 = csr_src[e + 2];
    const int s3 = csr_src[e + 3];
    const float n0 = dv * dinv[s0];
    const float n1 = dv * dinv[s1];
    const float n2 = dv * dinv[s2];
    const float n3 = dv * dinv[s3];
    const unsigned int r0 = hbf[(long)s0 * CW + lane];
    const unsigned int r1 = hbf[(long)s1 * CW + lane];
    const unsigned int r2 = hbf[(long)s2 * CW + lane];
    const unsigned int r3 = hbf[(long)s3 * CW + lane];
    a0 += n0 * bf2f((unsigned short)r0) + n1 * bf2f((unsigned short)r1) +
          n2 * bf2f((unsigned short)r2) + n3 * bf2f((unsigned short)r3);
    a1 += n0 * bf2f((unsigned short)(r0 >> 16)) + n1 * bf2f((unsigned short)(r1 >> 16)) +
          n2 * bf2f((unsigned short)(r2 >> 16)) + n3 * bf2f((unsigned short)(r3 >> 16));
  }
  for (; e < re; ++e) {
    const int s0 = csr_src[e];
    const float n0 = dv * dinv[s0];
    const unsigned int r0 = hbf[(long)s0 * CW + lane];
    a0 += n0 * bf2f((unsigned short)r0);
    a1 += n0 * bf2f((unsigned short)(r0 >> 16));
  }

  const float s2 = dv * dv;
  const unsigned int hv = hbf[(long)v * CW + lane];
  float o0 = s2 * bf2f((unsigned short)hv) + a0;
  float o1 = s2 * bf2f((unsigned short)(hv >> 16)) + a1;
  if (HAS_BIAS) {
    const float2 bv = *(const float2*)(bias + lane * 2);
    o0 += bv.x;
    o1 += bv.y;
  }
  if (OUT_HL) {
    uint2 u = {packHL(o0), packHL(o1)};
    *(uint2*)(outHL + (long)v * C + lane * 2) = u;
  } else {
    const float2 o = {o0, o1};
    *(float2*)(out + (long)v * C + lane * 2) = o;
  }
}

// ---------------------------------------------------------------------------
extern "C" void kernel_launch(void* const* d_in, const int* in_sizes, int n_in,
                              void* d_out, int out_size, void* d_ws, size_t ws_size,
                              hipStream_t stream) {
  (void)in_sizes; (void)n_in; (void)out_size; (void)ws_size;

  const float* x  = (const float*)d_in[0];
  const int*   ei = (const int*)d_in[1];
  const float* W1 = (const float*)d_in[2];
  const float* b1 = (const float*)d_in[3];
  const float* W2 = (const float*)d_in[4];
  const float* b2 = (const float*)d_in[5];
  float* out = (float*)d_out;

  // Workspace layout (bytes):
  char* ws = (char*)d_ws;
  uint2* edata    = (uint2*)(ws + 0);          //  6.4 MB {dst|rank<<16, src}
  int*   csr_src  = (int*)(ws + 6400000);      //  3.2 MB
  int*   deg      = (int*)(ws + 9600000);      //  0.2 MB
  int*   rowstart = (int*)(ws + 9800000);      //  0.2 MB (N+1)
  float* dinv     = (float*)(ws + 10000016);   //  0.2 MB
  int*   bsum     = (int*)(ws + 10200016);
  int*   boff     = (int*)(ws + 10201040);
  unsigned int* w1hl   = (unsigned int*)(ws + 10300000);  // 131 KB
  unsigned int* w2hl   = (unsigned int*)(ws + 10500000);  // 131 KB
  unsigned int* aggxHL = (unsigned int*)(ws + 11000000);  // 25.6 MB
  unsigned int* h2bf   = (unsigned int*)(ws + 11000000);  // 12.8 MB alias (aggx dead)
  unsigned int* h1hl   = (unsigned int*)(ws + 40000000);  // 51.2 MB
  unsigned int* xbf    = (unsigned int*)(ws + 91200000);  // 12.8 MB

  const int EB = (N_EDGES + 255) / 256;  // 3125
  const int GB = (N_NODES + 3) / 4;      // gather: 1 node/wave

  // ---- Graph preprocessing: CSR by destination + dinv ----
  deg_zero_k<<<NBLK, 256, 0, stream>>>(deg);
  convert_count_k<<<EB, 256, 0, stream>>>(ei, edata, deg);
  bsum_k<<<NBLK, 256, 0, stream>>>(deg, bsum);
  bscan_k<<<1, 256, 0, stream>>>(bsum, boff);
  bfinal_k<<<NBLK, 256, 0, stream>>>(deg, boff, rowstart, dinv);
  fill_csr_part_k<<<EB * NPART, 256, 0, stream>>>(edata, rowstart, csr_src);

  // ---- Operand conversions ----
  split_k<<<(HID_C * IN_C + 255) / 256, 256, 0, stream>>>(W1, w1hl, HID_C * IN_C);
  split_k<<<(OUT_C * HID_C + 255) / 256, 256, 0, stream>>>(W2, w2hl, OUT_C * HID_C);
  f2bf2_k<<<(N_NODES * IN_C / 4 + 255) / 256, 256, 0, stream>>>(
      x, xbf, N_NODES * IN_C / 4);

  // ---- Layer 1: aggx = agg(x_bf16) (HL out); h1 = relu(aggx@W1^T+b1) (HL out)
  gather_k<IN_C, false, true><<<GB, 256, 0, stream>>>(
      rowstart, csr_src, dinv, xbf, nullptr, nullptr, aggxHL);
  gemm_mfma_k<IN_C, HID_C, 64, 0><<<(N_NODES + 63) / 64, 256, 0, stream>>>(
      aggxHL, w1hl, b1, h1hl, nullptr);

  // ---- Layer 2: h2 = h1@W2^T (packed bf16 out); out = agg(h2_bf16) + b2
  gemm_mfma_k<HID_C, OUT_C, 32, 1><<<(N_NODES + 31) / 32, 256, 0, stream>>>(
      h1hl, w2hl, nullptr, nullptr, h2bf);
  gather_k<OUT_C, true, false><<<GB, 256, 0, stream>>>(
      rowstart, csr_src, dinv, h2bf, b2, out, nullptr);
}

// Round 16
// 207.081 us; speedup vs baseline: 1.8642x; 1.1000x over previous
//
#include <hip/hip_runtime.h>

#define N_NODES 50000
#define N_EDGES 800000
#define IN_C 128
#define HID_C 256
#define OUT_C 128
#define NBLK 196   // ceil(N_NODES / 256)
#define NPART 8    // XCD count; partition width = N_NODES/8 = 6250

typedef __attribute__((ext_vector_type(8))) short short8v;  // 8 bf16
typedef __attribute__((ext_vector_type(4))) float f32x4;

static __device__ __forceinline__ unsigned short f2bf(float f) {
  unsigned int u = __float_as_uint(f);
  unsigned int r = (u + 0x7fffu + ((u >> 16) & 1u)) >> 16;  // RNE
  return (unsigned short)r;
}
static __device__ __forceinline__ float bf2f(unsigned short h) {
  return __uint_as_float(((unsigned int)h) << 16);
}
// HL format: u32 = hi_bf16 | lo_bf16<<16, hi+lo ~= 16 mantissa bits of fp32.
static __device__ __forceinline__ unsigned int packHL(float v) {
  const unsigned short h = f2bf(v);
  const unsigned short l = f2bf(v - bf2f(h));
  return (unsigned int)h | ((unsigned int)l << 16);
}
// bf16 pair packing: u32 = bf(a) | bf(b)<<16  (natural k-order pairs)
static __device__ __forceinline__ unsigned int packBF2(float a, float b) {
  return (unsigned int)f2bf(a) | ((unsigned int)f2bf(b) << 16);
}
static __device__ __forceinline__ void unpackHL_g(const unsigned int* __restrict__ p,
                                                  short8v& hi, short8v& lo) {
  const uint4 a = *(const uint4*)p;
  const uint4 b = *(const uint4*)(p + 4);
  union { unsigned int u[4]; short8v s; } H, L;
  H.u[0] = (a.x & 0xffffu) | (a.y << 16);
  H.u[1] = (a.z & 0xffffu) | (a.w << 16);
  H.u[2] = (b.x & 0xffffu) | (b.y << 16);
  H.u[3] = (b.z & 0xffffu) | (b.w << 16);
  L.u[0] = (a.x >> 16) | (a.y & 0xffff0000u);
  L.u[1] = (a.z >> 16) | (a.w & 0xffff0000u);
  L.u[2] = (b.x >> 16) | (b.y & 0xffff0000u);
  L.u[3] = (b.z >> 16) | (b.w & 0xffff0000u);
  hi = H.s;
  lo = L.s;
}

// ---------------------------------------------------------------------------
// Edge conversion (int32/int64 auto-detect) + dst-degree histogram.
// atomicAdd return value = edge's rank within its dst-bucket; pack
// edata[e] = { dst | rank<<16 , src }.
// ---------------------------------------------------------------------------
__global__ __launch_bounds__(256) void deg_zero_k(int* __restrict__ deg) {
  const int i = blockIdx.x * 256 + threadIdx.x;
  if (i < N_NODES) deg[i] = 0;
}

__global__ __launch_bounds__(256) void convert_count_k(const int* __restrict__ ei,
                                                       uint2* __restrict__ edata,
                                                       int* __restrict__ deg) {
  __shared__ int s_is64;
  if (threadIdx.x == 0) {
    int nz = 0;
#pragma unroll
    for (int k = 0; k < 64; ++k) nz |= ei[2 * k + 1];
    s_is64 = (nz == 0) ? 1 : 0;
  }
  __syncthreads();
  const int is64 = s_is64;
  const int e = blockIdx.x * 256 + threadIdx.x;
  if (e < N_EDGES) {
    int s, d;
    if (is64) {
      const uint2 sv = ((const uint2*)ei)[e];             // 8B load, low word = src
      const uint2 dv = ((const uint2*)ei)[N_EDGES + e];   // 8B load, low word = dst
      s = (int)sv.x;
      d = (int)dv.x;
    } else {
      s = ei[e];
      d = ei[N_EDGES + e];
    }
    const int r = atomicAdd(&deg[d], 1);  // rank within bucket
    const uint2 t = {(unsigned int)d | ((unsigned int)r << 16), (unsigned int)s};
    edata[e] = t;
  }
}

// ---------------------------------------------------------------------------
// Parallel 3-phase exclusive scan over deg (bsum / bscan / bfinal+dinv).
// ---------------------------------------------------------------------------
__global__ __launch_bounds__(256) void bsum_k(const int* __restrict__ deg,
                                              int* __restrict__ bsum) {
  const int i = blockIdx.x * 256 + threadIdx.x;
  int v = (i < N_NODES) ? deg[i] : 0;
#pragma unroll
  for (int off = 32; off > 0; off >>= 1) v += __shfl_down(v, off, 64);
  __shared__ int ws[4];
  if ((threadIdx.x & 63) == 0) ws[threadIdx.x >> 6] = v;
  __syncthreads();
  if (threadIdx.x == 0) bsum[blockIdx.x] = ws[0] + ws[1] + ws[2] + ws[3];
}

__global__ __launch_bounds__(256) void bscan_k(const int* __restrict__ bsum,
                                               int* __restrict__ boff) {
  __shared__ int s[256];
  const int t = threadIdx.x;
  const int v = (t < NBLK) ? bsum[t] : 0;
  s[t] = v;
  __syncthreads();
  for (int off = 1; off < 256; off <<= 1) {
    const int tmp = (t >= off) ? s[t - off] : 0;
    __syncthreads();
    s[t] += tmp;
    __syncthreads();
  }
  if (t < NBLK) boff[t] = s[t] - v;
}

__global__ __launch_bounds__(256) void bfinal_k(const int* __restrict__ deg,
                                                const int* __restrict__ boff,
                                                int* __restrict__ rowstart,
                                                float* __restrict__ dinv) {
  __shared__ int s[256];
  const int t = threadIdx.x;
  const int i = blockIdx.x * 256 + t;
  const int d = (i < N_NODES) ? deg[i] : 0;
  s[t] = d;
  __syncthreads();
  for (int off = 1; off < 256; off <<= 1) {
    const int tmp = (t >= off) ? s[t - off] : 0;
    __syncthreads();
    s[t] += tmp;
    __syncthreads();
  }
  const int run = boff[blockIdx.x] + s[t] - d;
  if (i < N_NODES) {
    rowstart[i] = run;
    dinv[i] = rsqrtf((float)d + 1.0f);
    if (i == N_NODES - 1) rowstart[N_NODES] = run + d;
  }
}

// ---------------------------------------------------------------------------
// XCD-partitioned, atomic-free CSR fill (partition p = bx&7 => one dst-range
// per XCD; bucket-contiguous csr lines coalesce in that XCD's L2).
// ---------------------------------------------------------------------------
__global__ __launch_bounds__(256) void fill_csr_part_k(const uint2* __restrict__ edata,
                                                       const int* __restrict__ rowstart,
                                                       int* __restrict__ csr_src) {
  const int p = blockIdx.x & 7;
  const int e = (blockIdx.x >> 3) * 256 + threadIdx.x;
  if (e < N_EDGES) {
    const uint2 t = edata[e];
    const int d = t.x & 0xffff;
    const int r = t.x >> 16;
    if (d / 6250 == p) csr_src[rowstart[d] + r] = (int)t.y;
  }
}

// ---------------------------------------------------------------------------
// Weight split: fp32 -> HL u32. x convert: fp32 -> packed bf16 pairs.
// ---------------------------------------------------------------------------
__global__ __launch_bounds__(256) void split_k(const float* __restrict__ in,
                                               unsigned int* __restrict__ hl,
                                               int n) {
  const int i = blockIdx.x * 256 + threadIdx.x;
  if (i < n) hl[i] = packHL(in[i]);
}

__global__ __launch_bounds__(256) void f2bf2_k(const float* __restrict__ in,
                                               unsigned int* __restrict__ outp,
                                               int n4) {  // n4 = n/4
  const int i = blockIdx.x * 256 + threadIdx.x;
  if (i < n4) {
    const float4 f = *(const float4*)(in + i * 4);
    uint2 u = {packBF2(f.x, f.y), packBF2(f.z, f.w)};
    *(uint2*)(outp + i * 2) = u;
  }
}

// ---------------------------------------------------------------------------
// LDS-staged MFMA GEMM, swapped operand order, W in HL (split) format.
// XHL=1: X is HL u32 (3 MFMA passes, 16-bit-mantissa X). XHL=0: X is packed
// bf16 pairs in k-order (frag = direct reinterpret, 2 MFMA passes).
// Output: packed bf16 uint2 (optionally bias+relu first).
// ---------------------------------------------------------------------------
template <int K, int MTOT, int NT, bool XHL, bool BIASRELU>
__global__ __launch_bounds__(256) void gemm_mfma_k(
    const unsigned int* __restrict__ X, const unsigned int* __restrict__ WHL,
    const float* __restrict__ bias, unsigned int* __restrict__ outBF) {
  constexpr int XW = XHL ? K : K / 2;  // u32 words per X row
  constexpr int KP = XW + 4;           // padded LDS row stride
  constexpr int MW = MTOT / 4;
  constexpr int NMT = MW / 16;
  constexpr int NNT = NT / 16;
  constexpr int NKS = K / 32;
  __shared__ unsigned int xs[NT * KP];

  const int tid = threadIdx.x;
  const int w = tid >> 6;
  const int l = tid & 63;
  const long nbase = (long)blockIdx.x * NT;

  constexpr int SIT = (NT * XW) / (256 * 4);
#pragma unroll
  for (int i = 0; i < SIT; ++i) {
    const int idx = (tid + i * 256) * 4;
    const int row = idx / XW, col = idx % XW;
    long gr = nbase + row;
    if (gr > N_NODES - 1) gr = N_NODES - 1;
    const uint4 v = *(const uint4*)(X + gr * XW + col);
    *(uint4*)(xs + row * KP + col) = v;
  }
  __syncthreads();

  const int m0w = w * MW;
  const int kg = (l >> 4) * 8;
  const int lr = l & 15;

  f32x4 acc[NNT][NMT];
#pragma unroll
  for (int nt = 0; nt < NNT; ++nt)
#pragma unroll
    for (int mt = 0; mt < NMT; ++mt) acc[nt][mt] = {0.0f, 0.0f, 0.0f, 0.0f};

#pragma unroll
  for (int ks = 0; ks < NKS; ++ks) {
    const int ko = ks * 32 + kg;
    short8v wHi[NMT], wLo[NMT];
#pragma unroll
    for (int mt = 0; mt < NMT; ++mt)
      unpackHL_g(WHL + (long)(m0w + mt * 16 + lr) * K + ko, wHi[mt], wLo[mt]);
#pragma unroll
    for (int nt = 0; nt < NNT; ++nt) {
      if (XHL) {
        short8v xHi, xLo;
        unpackHL_g(xs + (nt * 16 + lr) * KP + ko, xHi, xLo);
#pragma unroll
        for (int mt = 0; mt < NMT; ++mt) {
          acc[nt][mt] = __builtin_amdgcn_mfma_f32_16x16x32_bf16(wHi[mt], xHi,
                                                               acc[nt][mt], 0, 0, 0);
          acc[nt][mt] = __builtin_amdgcn_mfma_f32_16x16x32_bf16(wLo[mt], xHi,
                                                               acc[nt][mt], 0, 0, 0);
          acc[nt][mt] = __builtin_amdgcn_mfma_f32_16x16x32_bf16(wHi[mt], xLo,
                                                               acc[nt][mt], 0, 0, 0);
        }
      } else {
        const short8v xbf = *(const short8v*)(xs + (nt * 16 + lr) * KP + ko / 2);
#pragma unroll
        for (int mt = 0; mt < NMT; ++mt) {
          acc[nt][mt] = __builtin_amdgcn_mfma_f32_16x16x32_bf16(wHi[mt], xbf,
                                                               acc[nt][mt], 0, 0, 0);
          acc[nt][mt] = __builtin_amdgcn_mfma_f32_16x16x32_bf16(wLo[mt], xbf,
                                                               acc[nt][mt], 0, 0, 0);
        }
      }
    }
  }

  const int mq0 = (l >> 4) * 4;
#pragma unroll
  for (int nt = 0; nt < NNT; ++nt) {
    const long n = nbase + nt * 16 + lr;
    if (n < N_NODES) {
#pragma unroll
      for (int mt = 0; mt < NMT; ++mt) {
        const int mq = m0w + mt * 16 + mq0;
        float v0 = acc[nt][mt][0], v1 = acc[nt][mt][1];
        float v2 = acc[nt][mt][2], v3 = acc[nt][mt][3];
        if (BIASRELU) {
          const float4 bv = *(const float4*)(bias + mq);
          v0 = fmaxf(v0 + bv.x, 0.0f);
          v1 = fmaxf(v1 + bv.y, 0.0f);
          v2 = fmaxf(v2 + bv.z, 0.0f);
          v3 = fmaxf(v3 + bv.w, 0.0f);
        }
        uint2 o = {packBF2(v0, v1), packBF2(v2, v3)};
        *(uint2*)(outBF + n * (MTOT / 2) + mq / 2) = o;
      }
    }
  }
}

// ---------------------------------------------------------------------------
// Gather-aggregate (one wave per destination node) over PACKED-BF16 rows.
// Lane reads 1 u32 = 2 channels per row. 8-edge unroll for MLP.
// OUT_HL: write HL u32 pair (feeds GEMM1, 16-bit-mantissa). Else fp32 final.
// ---------------------------------------------------------------------------
template <int C, bool HAS_BIAS, bool OUT_HL>
__global__ __launch_bounds__(256) void gather_k(const int* __restrict__ rowstart,
                                                const int* __restrict__ csr_src,
                                                const float* __restrict__ dinv,
                                                const unsigned int* __restrict__ hbf,
                                                const float* __restrict__ bias,
                                                float* __restrict__ out,
                                                unsigned int* __restrict__ outHL) {
  const int v = (blockIdx.x * 256 + threadIdx.x) >> 6;
  if (v >= N_NODES) return;
  const int lane = threadIdx.x & 63;
  constexpr int CW = C / 2;  // u32 words per row
  const int rs = rowstart[v];
  const int re = rowstart[v + 1];
  const float dv = dinv[v];

  float a0 = 0.0f, a1 = 0.0f;

  int e = rs;
  for (; e + 7 < re; e += 8) {
    int s[8];
    float nn[8];
    unsigned int r[8];
#pragma unroll
    for (int j = 0; j < 8; ++j) s[j] = csr_src[e + j];
#pragma unroll
    for (int j = 0; j < 8; ++j) nn[j] = dv * dinv[s[j]];
#pragma unroll
    for (int j = 0; j < 8; ++j) r[j] = hbf[(long)s[j] * CW + lane];
#pragma unroll
    for (int j = 0; j < 8; ++j) {
      a0 += nn[j] * bf2f((unsigned short)r[j]);
      a1 += nn[j] * bf2f((unsigned short)(r[j] >> 16));
    }
  }
  for (; e + 3 < re; e += 4) {
    int s[4];
    float nn[4];
    unsigned int r[4];
#pragma unroll
    for (int j = 0; j < 4; ++j) s[j] = csr_src[e + j];
#pragma unroll
    for (int j = 0; j < 4; ++j) nn[j] = dv * dinv[s[j]];
#pragma unroll
    for (int j = 0; j < 4; ++j) r[j] = hbf[(long)s[j] * CW + lane];
#pragma unroll
    for (int j = 0; j < 4; ++j) {
      a0 += nn[j] * bf2f((unsigned short)r[j]);
      a1 += nn[j] * bf2f((unsigned short)(r[j] >> 16));
    }
  }
  for (; e < re; ++e) {
    const int s0 = csr_src[e];
    const float n0 = dv * dinv[s0];
    const unsigned int r0 = hbf[(long)s0 * CW + lane];
    a0 += n0 * bf2f((unsigned short)r0);
    a1 += n0 * bf2f((unsigned short)(r0 >> 16));
  }

  const float s2 = dv * dv;
  const unsigned int hv = hbf[(long)v * CW + lane];
  float o0 = s2 * bf2f((unsigned short)hv) + a0;
  float o1 = s2 * bf2f((unsigned short)(hv >> 16)) + a1;
  if (HAS_BIAS) {
    const float2 bv = *(const float2*)(bias + lane * 2);
    o0 += bv.x;
    o1 += bv.y;
  }
  if (OUT_HL) {
    uint2 u = {packHL(o0), packHL(o1)};
    *(uint2*)(outHL + (long)v * C + lane * 2) = u;
  } else {
    const float2 o = {o0, o1};
    *(float2*)(out + (long)v * C + lane * 2) = o;
  }
}

// ---------------------------------------------------------------------------
extern "C" void kernel_launch(void* const* d_in, const int* in_sizes, int n_in,
                              void* d_out, int out_size, void* d_ws, size_t ws_size,
                              hipStream_t stream) {
  (void)in_sizes; (void)n_in; (void)out_size; (void)ws_size;

  const float* x  = (const float*)d_in[0];
  const int*   ei = (const int*)d_in[1];
  const float* W1 = (const float*)d_in[2];
  const float* b1 = (const float*)d_in[3];
  const float* W2 = (const float*)d_in[4];
  const float* b2 = (const float*)d_in[5];
  float* out = (float*)d_out;

  // Workspace layout (bytes):
  char* ws = (char*)d_ws;
  uint2* edata    = (uint2*)(ws + 0);          //  6.4 MB {dst|rank<<16, src}
  int*   csr_src  = (int*)(ws + 6400000);      //  3.2 MB
  int*   deg      = (int*)(ws + 9600000);      //  0.2 MB
  int*   rowstart = (int*)(ws + 9800000);      //  0.2 MB (N+1)
  float* dinv     = (float*)(ws + 10000016);   //  0.2 MB
  int*   bsum     = (int*)(ws + 10200016);
  int*   boff     = (int*)(ws + 10201040);
  unsigned int* w1hl   = (unsigned int*)(ws + 10300000);  // 131 KB
  unsigned int* w2hl   = (unsigned int*)(ws + 10500000);  // 131 KB
  unsigned int* aggxHL = (unsigned int*)(ws + 11000000);  // 25.6 MB
  unsigned int* h2bf   = (unsigned int*)(ws + 11000000);  // 12.8 MB alias (aggx dead)
  unsigned int* h1bf   = (unsigned int*)(ws + 40000000);  // 25.6 MB (bf16 packed)
  unsigned int* xbf    = (unsigned int*)(ws + 91200000);  // 12.8 MB

  const int EB = (N_EDGES + 255) / 256;  // 3125
  const int GB = (N_NODES + 3) / 4;      // gather: 1 node/wave

  // ---- Graph preprocessing: CSR by destination + dinv ----
  deg_zero_k<<<NBLK, 256, 0, stream>>>(deg);
  convert_count_k<<<EB, 256, 0, stream>>>(ei, edata, deg);
  bsum_k<<<NBLK, 256, 0, stream>>>(deg, bsum);
  bscan_k<<<1, 256, 0, stream>>>(bsum, boff);
  bfinal_k<<<NBLK, 256, 0, stream>>>(deg, boff, rowstart, dinv);
  fill_csr_part_k<<<EB * NPART, 256, 0, stream>>>(edata, rowstart, csr_src);

  // ---- Operand conversions ----
  split_k<<<(HID_C * IN_C + 255) / 256, 256, 0, stream>>>(W1, w1hl, HID_C * IN_C);
  split_k<<<(OUT_C * HID_C + 255) / 256, 256, 0, stream>>>(W2, w2hl, OUT_C * HID_C);
  f2bf2_k<<<(N_NODES * IN_C / 4 + 255) / 256, 256, 0, stream>>>(
      x, xbf, N_NODES * IN_C / 4);

  // ---- Layer 1: aggx = agg(x_bf16) (HL out); h1 = relu(aggx@W1^T+b1) (bf16 out)
  gather_k<IN_C, false, true><<<GB, 256, 0, stream>>>(
      rowstart, csr_src, dinv, xbf, nullptr, nullptr, aggxHL);
  gemm_mfma_k<IN_C, HID_C, 64, true, true>
      <<<(N_NODES + 63) / 64, 256, 0, stream>>>(aggxHL, w1hl, b1, h1bf);

  // ---- Layer 2: h2 = h1_bf16@W2^T (bf16 out, 2-pass); out = agg(h2_bf16) + b2
  gemm_mfma_k<HID_C, OUT_C, 64, false, false>
      <<<(N_NODES + 63) / 64, 256, 0, stream>>>(h1bf, w2hl, nullptr, h2bf);
  gather_k<OUT_C, true, false><<<GB, 256, 0, stream>>>(
      rowstart, csr_src, dinv, h2bf, b2, out, nullptr);
}

// Round 17
// 199.453 us; speedup vs baseline: 1.9355x; 1.0382x over previous
//
#include <hip/hip_runtime.h>

#define N_NODES 50000
#define N_EDGES 800000
#define IN_C 128
#define HID_C 256
#define OUT_C 128
#define NBLK 196   // ceil(N_NODES / 256)
#define NPART 8    // XCD count; partition width = N_NODES/8 = 6250
#define XCONV_BLKS 6250  // N_NODES*IN_C/4 / 256
#define WCONV_BLKS 128   // 32768 / 256

typedef __attribute__((ext_vector_type(8))) short short8v;  // 8 bf16
typedef __attribute__((ext_vector_type(4))) float f32x4;

static __device__ __forceinline__ unsigned short f2bf(float f) {
  unsigned int u = __float_as_uint(f);
  unsigned int r = (u + 0x7fffu + ((u >> 16) & 1u)) >> 16;  // RNE
  return (unsigned short)r;
}
static __device__ __forceinline__ float bf2f(unsigned short h) {
  return __uint_as_float(((unsigned int)h) << 16);
}
// HL format: u32 = hi_bf16 | lo_bf16<<16, hi+lo ~= 16 mantissa bits of fp32.
static __device__ __forceinline__ unsigned int packHL(float v) {
  const unsigned short h = f2bf(v);
  const unsigned short l = f2bf(v - bf2f(h));
  return (unsigned int)h | ((unsigned int)l << 16);
}
// bf16 pair packing: u32 = bf(a) | bf(b)<<16  (natural k-order pairs)
static __device__ __forceinline__ unsigned int packBF2(float a, float b) {
  return (unsigned int)f2bf(a) | ((unsigned int)f2bf(b) << 16);
}
static __device__ __forceinline__ void unpackHL_g(const unsigned int* __restrict__ p,
                                                  short8v& hi, short8v& lo) {
  const uint4 a = *(const uint4*)p;
  const uint4 b = *(const uint4*)(p + 4);
  union { unsigned int u[4]; short8v s; } H, L;
  H.u[0] = (a.x & 0xffffu) | (a.y << 16);
  H.u[1] = (a.z & 0xffffu) | (a.w << 16);
  H.u[2] = (b.x & 0xffffu) | (b.y << 16);
  H.u[3] = (b.z & 0xffffu) | (b.w << 16);
  L.u[0] = (a.x >> 16) | (a.y & 0xffff0000u);
  L.u[1] = (a.z >> 16) | (a.w & 0xffff0000u);
  L.u[2] = (b.x >> 16) | (b.y & 0xffff0000u);
  L.u[3] = (b.z >> 16) | (b.w & 0xffff0000u);
  hi = H.s;
  lo = L.s;
}

// ---------------------------------------------------------------------------
// Edge conversion (int32/int64 auto-detect) + dst-degree histogram.
// atomicAdd return value = edge's rank within its dst-bucket; pack
// edata[e] = { dst | rank<<16 , src }. deg must be pre-zeroed (memset).
// ---------------------------------------------------------------------------
__global__ __launch_bounds__(256) void convert_count_k(const int* __restrict__ ei,
                                                       uint2* __restrict__ edata,
                                                       int* __restrict__ deg) {
  __shared__ int s_is64;
  if (threadIdx.x == 0) {
    int nz = 0;
#pragma unroll
    for (int k = 0; k < 64; ++k) nz |= ei[2 * k + 1];
    s_is64 = (nz == 0) ? 1 : 0;
  }
  __syncthreads();
  const int is64 = s_is64;
  const int e = blockIdx.x * 256 + threadIdx.x;
  if (e < N_EDGES) {
    int s, d;
    if (is64) {
      const uint2 sv = ((const uint2*)ei)[e];            // 8B load, low word = src
      const uint2 dv = ((const uint2*)ei)[N_EDGES + e];  // 8B load, low word = dst
      s = (int)sv.x;
      d = (int)dv.x;
    } else {
      s = ei[e];
      d = ei[N_EDGES + e];
    }
    const int r = atomicAdd(&deg[d], 1);  // rank within bucket
    const uint2 t = {(unsigned int)d | ((unsigned int)r << 16), (unsigned int)s};
    edata[e] = t;
  }
}

// ---------------------------------------------------------------------------
// Parallel 3-phase exclusive scan over deg (bsum / bscan / bfinal+dinv).
// ---------------------------------------------------------------------------
__global__ __launch_bounds__(256) void bsum_k(const int* __restrict__ deg,
                                              int* __restrict__ bsum) {
  const int i = blockIdx.x * 256 + threadIdx.x;
  int v = (i < N_NODES) ? deg[i] : 0;
#pragma unroll
  for (int off = 32; off > 0; off >>= 1) v += __shfl_down(v, off, 64);
  __shared__ int ws[4];
  if ((threadIdx.x & 63) == 0) ws[threadIdx.x >> 6] = v;
  __syncthreads();
  if (threadIdx.x == 0) bsum[blockIdx.x] = ws[0] + ws[1] + ws[2] + ws[3];
}

__global__ __launch_bounds__(256) void bscan_k(const int* __restrict__ bsum,
                                               int* __restrict__ boff) {
  __shared__ int s[256];
  const int t = threadIdx.x;
  const int v = (t < NBLK) ? bsum[t] : 0;
  s[t] = v;
  __syncthreads();
  for (int off = 1; off < 256; off <<= 1) {
    const int tmp = (t >= off) ? s[t - off] : 0;
    __syncthreads();
    s[t] += tmp;
    __syncthreads();
  }
  if (t < NBLK) boff[t] = s[t] - v;
}

__global__ __launch_bounds__(256) void bfinal_k(const int* __restrict__ deg,
                                                const int* __restrict__ boff,
                                                int* __restrict__ rowstart,
                                                float* __restrict__ dinv) {
  __shared__ int s[256];
  const int t = threadIdx.x;
  const int i = blockIdx.x * 256 + t;
  const int d = (i < N_NODES) ? deg[i] : 0;
  s[t] = d;
  __syncthreads();
  for (int off = 1; off < 256; off <<= 1) {
    const int tmp = (t >= off) ? s[t - off] : 0;
    __syncthreads();
    s[t] += tmp;
    __syncthreads();
  }
  const int run = boff[blockIdx.x] + s[t] - d;
  if (i < N_NODES) {
    rowstart[i] = run;
    dinv[i] = rsqrtf((float)d + 1.0f);
    if (i == N_NODES - 1) rowstart[N_NODES] = run + d;
  }
}

// ---------------------------------------------------------------------------
// XCD-partitioned, atomic-free CSR fill (partition p = bx&7 => one dst-range
// per XCD; bucket-contiguous csr lines coalesce in that XCD's L2).
// ---------------------------------------------------------------------------
__global__ __launch_bounds__(256) void fill_csr_part_k(const uint2* __restrict__ edata,
                                                       const int* __restrict__ rowstart,
                                                       int* __restrict__ csr_src) {
  const int p = blockIdx.x & 7;
  const int e = (blockIdx.x >> 3) * 256 + threadIdx.x;
  if (e < N_EDGES) {
    const uint2 t = edata[e];
    const int d = t.x & 0xffff;
    const int r = t.x >> 16;
    if (d / 6250 == p) csr_src[rowstart[d] + r] = (int)t.y;
  }
}

// ---------------------------------------------------------------------------
// Fused operand conversion: blocks [0,6250) convert x -> packed bf16;
// [6250,6378) split W1 -> HL; [6378,6506) split W2 -> HL.
// ---------------------------------------------------------------------------
__global__ __launch_bounds__(256) void conv_all_k(const float* __restrict__ x,
                                                  unsigned int* __restrict__ xbf,
                                                  const float* __restrict__ W1,
                                                  unsigned int* __restrict__ w1hl,
                                                  const float* __restrict__ W2,
                                                  unsigned int* __restrict__ w2hl) {
  const int b = blockIdx.x;
  if (b < XCONV_BLKS) {
    const int i = b * 256 + threadIdx.x;  // over N*C/4 float4s
    const float4 f = *(const float4*)(x + (long)i * 4);
    uint2 u = {packBF2(f.x, f.y), packBF2(f.z, f.w)};
    *(uint2*)(xbf + (long)i * 2) = u;
  } else if (b < XCONV_BLKS + WCONV_BLKS) {
    const int i = (b - XCONV_BLKS) * 256 + threadIdx.x;
    w1hl[i] = packHL(W1[i]);
  } else {
    const int i = (b - XCONV_BLKS - WCONV_BLKS) * 256 + threadIdx.x;
    w2hl[i] = packHL(W2[i]);
  }
}

// ---------------------------------------------------------------------------
// LDS-staged MFMA GEMM, swapped operand order, W in HL (split, 2-pass) format,
// X in packed bf16 k-order pairs (direct frag reinterpret). Output packed bf16
// (optionally bias+relu first).
// ---------------------------------------------------------------------------
template <int K, int MTOT, int NT, bool BIASRELU>
__global__ __launch_bounds__(256) void gemm_mfma_k(
    const unsigned int* __restrict__ X, const unsigned int* __restrict__ WHL,
    const float* __restrict__ bias, unsigned int* __restrict__ outBF) {
  constexpr int XW = K / 2;   // u32 words per X row
  constexpr int KP = XW + 4;  // padded LDS row stride
  constexpr int MW = MTOT / 4;
  constexpr int NMT = MW / 16;
  constexpr int NNT = NT / 16;
  constexpr int NKS = K / 32;
  __shared__ unsigned int xs[NT * KP];

  const int tid = threadIdx.x;
  const int w = tid >> 6;
  const int l = tid & 63;
  const long nbase = (long)blockIdx.x * NT;

  constexpr int SIT = (NT * XW) / (256 * 4);
#pragma unroll
  for (int i = 0; i < SIT; ++i) {
    const int idx = (tid + i * 256) * 4;
    const int row = idx / XW, col = idx % XW;
    long gr = nbase + row;
    if (gr > N_NODES - 1) gr = N_NODES - 1;
    const uint4 v = *(const uint4*)(X + gr * XW + col);
    *(uint4*)(xs + row * KP + col) = v;
  }
  __syncthreads();

  const int m0w = w * MW;
  const int kg = (l >> 4) * 8;
  const int lr = l & 15;

  f32x4 acc[NNT][NMT];
#pragma unroll
  for (int nt = 0; nt < NNT; ++nt)
#pragma unroll
    for (int mt = 0; mt < NMT; ++mt) acc[nt][mt] = {0.0f, 0.0f, 0.0f, 0.0f};

#pragma unroll
  for (int ks = 0; ks < NKS; ++ks) {
    const int ko = ks * 32 + kg;
    short8v wHi[NMT], wLo[NMT];
#pragma unroll
    for (int mt = 0; mt < NMT; ++mt)
      unpackHL_g(WHL + (long)(m0w + mt * 16 + lr) * K + ko, wHi[mt], wLo[mt]);
#pragma unroll
    for (int nt = 0; nt < NNT; ++nt) {
      const short8v xbf = *(const short8v*)(xs + (nt * 16 + lr) * KP + ko / 2);
#pragma unroll
      for (int mt = 0; mt < NMT; ++mt) {
        acc[nt][mt] = __builtin_amdgcn_mfma_f32_16x16x32_bf16(wHi[mt], xbf,
                                                             acc[nt][mt], 0, 0, 0);
        acc[nt][mt] = __builtin_amdgcn_mfma_f32_16x16x32_bf16(wLo[mt], xbf,
                                                             acc[nt][mt], 0, 0, 0);
      }
    }
  }

  const int mq0 = (l >> 4) * 4;
#pragma unroll
  for (int nt = 0; nt < NNT; ++nt) {
    const long n = nbase + nt * 16 + lr;
    if (n < N_NODES) {
#pragma unroll
      for (int mt = 0; mt < NMT; ++mt) {
        const int mq = m0w + mt * 16 + mq0;
        float v0 = acc[nt][mt][0], v1 = acc[nt][mt][1];
        float v2 = acc[nt][mt][2], v3 = acc[nt][mt][3];
        if (BIASRELU) {
          const float4 bv = *(const float4*)(bias + mq);
          v0 = fmaxf(v0 + bv.x, 0.0f);
          v1 = fmaxf(v1 + bv.y, 0.0f);
          v2 = fmaxf(v2 + bv.z, 0.0f);
          v3 = fmaxf(v3 + bv.w, 0.0f);
        }
        uint2 o = {packBF2(v0, v1), packBF2(v2, v3)};
        *(uint2*)(outBF + n * (MTOT / 2) + mq / 2) = o;
      }
    }
  }
}

// ---------------------------------------------------------------------------
// Gather-aggregate (one wave per destination node) over PACKED-BF16 rows.
// Lane reads 1 u32 = 2 channels per row. 8-edge unroll for MLP.
// OUT_BF: write packed bf16 u32 (feeds GEMM1). Else fp32 (+bias) final.
// ---------------------------------------------------------------------------
template <int C, bool HAS_BIAS, bool OUT_BF>
__global__ __launch_bounds__(256) void gather_k(const int* __restrict__ rowstart,
                                                const int* __restrict__ csr_src,
                                                const float* __restrict__ dinv,
                                                const unsigned int* __restrict__ hbf,
                                                const float* __restrict__ bias,
                                                float* __restrict__ out,
                                                unsigned int* __restrict__ outBF) {
  const int v = (blockIdx.x * 256 + threadIdx.x) >> 6;
  if (v >= N_NODES) return;
  const int lane = threadIdx.x & 63;
  constexpr int CW = C / 2;  // u32 words per row
  const int rs = rowstart[v];
  const int re = rowstart[v + 1];
  const float dv = dinv[v];

  float a0 = 0.0f, a1 = 0.0f;

  int e = rs;
  for (; e + 7 < re; e += 8) {
    int s[8];
    float nn[8];
    unsigned int r[8];
#pragma unroll
    for (int j = 0; j < 8; ++j) s[j] = csr_src[e + j];
#pragma unroll
    for (int j = 0; j < 8; ++j) nn[j] = dv * dinv[s[j]];
#pragma unroll
    for (int j = 0; j < 8; ++j) r[j] = hbf[(long)s[j] * CW + lane];
#pragma unroll
    for (int j = 0; j < 8; ++j) {
      a0 += nn[j] * bf2f((unsigned short)r[j]);
      a1 += nn[j] * bf2f((unsigned short)(r[j] >> 16));
    }
  }
  for (; e + 3 < re; e += 4) {
    int s[4];
    float nn[4];
    unsigned int r[4];
#pragma unroll
    for (int j = 0; j < 4; ++j) s[j] = csr_src[e + j];
#pragma unroll
    for (int j = 0; j < 4; ++j) nn[j] = dv * dinv[s[j]];
#pragma unroll
    for (int j = 0; j < 4; ++j) r[j] = hbf[(long)s[j] * CW + lane];
#pragma unroll
    for (int j = 0; j < 4; ++j) {
      a0 += nn[j] * bf2f((unsigned short)r[j]);
      a1 += nn[j] * bf2f((unsigned short)(r[j] >> 16));
    }
  }
  for (; e < re; ++e) {
    const int s0 = csr_src[e];
    const float n0 = dv * dinv[s0];
    const unsigned int r0 = hbf[(long)s0 * CW + lane];
    a0 += n0 * bf2f((unsigned short)r0);
    a1 += n0 * bf2f((unsigned short)(r0 >> 16));
  }

  const float s2 = dv * dv;
  const unsigned int hv = hbf[(long)v * CW + lane];
  float o0 = s2 * bf2f((unsigned short)hv) + a0;
  float o1 = s2 * bf2f((unsigned short)(hv >> 16)) + a1;
  if (HAS_BIAS) {
    const float2 bv = *(const float2*)(bias + lane * 2);
    o0 += bv.x;
    o1 += bv.y;
  }
  if (OUT_BF) {
    outBF[(long)v * CW + lane] = packBF2(o0, o1);
  } else {
    const float2 o = {o0, o1};
    *(float2*)(out + (long)v * CW * 2 + lane * 2) = o;
  }
}

// ---------------------------------------------------------------------------
extern "C" void kernel_launch(void* const* d_in, const int* in_sizes, int n_in,
                              void* d_out, int out_size, void* d_ws, size_t ws_size,
                              hipStream_t stream) {
  (void)in_sizes; (void)n_in; (void)out_size; (void)ws_size;

  const float* x  = (const float*)d_in[0];
  const int*   ei = (const int*)d_in[1];
  const float* W1 = (const float*)d_in[2];
  const float* b1 = (const float*)d_in[3];
  const float* W2 = (const float*)d_in[4];
  const float* b2 = (const float*)d_in[5];
  float* out = (float*)d_out;

  // Workspace layout (bytes):
  char* ws = (char*)d_ws;
  uint2* edata    = (uint2*)(ws + 0);          //  6.4 MB {dst|rank<<16, src}
  int*   csr_src  = (int*)(ws + 6400000);      //  3.2 MB
  int*   deg      = (int*)(ws + 9600000);      //  0.2 MB
  int*   rowstart = (int*)(ws + 9800000);      //  0.2 MB (N+1)
  float* dinv     = (float*)(ws + 10000016);   //  0.2 MB
  int*   bsum     = (int*)(ws + 10200016);
  int*   boff     = (int*)(ws + 10201040);
  unsigned int* w1hl   = (unsigned int*)(ws + 10300000);  // 131 KB
  unsigned int* w2hl   = (unsigned int*)(ws + 10500000);  // 131 KB
  unsigned int* aggxbf = (unsigned int*)(ws + 11000000);  // 12.8 MB (bf16 packed)
  unsigned int* h2bf   = (unsigned int*)(ws + 11000000);  // alias (aggx dead)
  unsigned int* h1bf   = (unsigned int*)(ws + 40000000);  // 25.6 MB (bf16 packed)
  unsigned int* xbf    = (unsigned int*)(ws + 91200000);  // 12.8 MB

  const int EB = (N_EDGES + 255) / 256;  // 3125
  const int GB = (N_NODES + 3) / 4;      // gather: 1 node/wave

  // ---- Graph preprocessing: CSR by destination + dinv ----
  hipMemsetAsync(deg, 0, N_NODES * sizeof(int), stream);
  convert_count_k<<<EB, 256, 0, stream>>>(ei, edata, deg);
  bsum_k<<<NBLK, 256, 0, stream>>>(deg, bsum);
  bscan_k<<<1, 256, 0, stream>>>(bsum, boff);
  bfinal_k<<<NBLK, 256, 0, stream>>>(deg, boff, rowstart, dinv);
  fill_csr_part_k<<<EB * NPART, 256, 0, stream>>>(edata, rowstart, csr_src);

  // ---- Fused operand conversions (x -> bf16, W1/W2 -> HL) ----
  conv_all_k<<<XCONV_BLKS + 2 * WCONV_BLKS, 256, 0, stream>>>(x, xbf, W1, w1hl,
                                                              W2, w2hl);

  // ---- Layer 1: aggx = agg(x_bf16) (bf16 out); h1 = relu(aggx@W1^T+b1) (bf16)
  gather_k<IN_C, false, true><<<GB, 256, 0, stream>>>(
      rowstart, csr_src, dinv, xbf, nullptr, nullptr, aggxbf);
  gemm_mfma_k<IN_C, HID_C, 64, true>
      <<<(N_NODES + 63) / 64, 256, 0, stream>>>(aggxbf, w1hl, b1, h1bf);

  // ---- Layer 2: h2 = h1_bf16@W2^T (bf16 out); out = agg(h2_bf16) + b2
  gemm_mfma_k<HID_C, OUT_C, 64, false>
      <<<(N_NODES + 63) / 64, 256, 0, stream>>>(h1bf, w2hl, nullptr, h2bf);
  gather_k<OUT_C, true, false><<<GB, 256, 0, stream>>>(
      rowstart, csr_src, dinv, h2bf, b2, out, nullptr);
}

// Round 18
// 182.838 us; speedup vs baseline: 2.1113x; 1.0909x over previous
//
#include <hip/hip_runtime.h>

#define N_NODES 50000
#define N_EDGES 800000
#define IN_C 128
#define HID_C 256
#define OUT_C 128
#define NBLK 196   // ceil(N_NODES / 256)
#define NPART 8    // XCD count; partition width = N_NODES/8 = 6250
#define XCONV_BLKS 6250  // N_NODES*IN_C/4 / 256
#define WCONV_BLKS 128   // 32768 / 256

typedef __attribute__((ext_vector_type(8))) short short8v;  // 8 bf16
typedef __attribute__((ext_vector_type(4))) float f32x4;

static __device__ __forceinline__ unsigned short f2bf(float f) {
  unsigned int u = __float_as_uint(f);
  unsigned int r = (u + 0x7fffu + ((u >> 16) & 1u)) >> 16;  // RNE
  return (unsigned short)r;
}
static __device__ __forceinline__ float bf2f(unsigned short h) {
  return __uint_as_float(((unsigned int)h) << 16);
}
// HL format: u32 = hi_bf16 | lo_bf16<<16, hi+lo ~= 16 mantissa bits of fp32.
static __device__ __forceinline__ unsigned int packHL(float v) {
  const unsigned short h = f2bf(v);
  const unsigned short l = f2bf(v - bf2f(h));
  return (unsigned int)h | ((unsigned int)l << 16);
}
// bf16 pair packing: u32 = bf(a) | bf(b)<<16  (natural k-order pairs)
static __device__ __forceinline__ unsigned int packBF2(float a, float b) {
  return (unsigned int)f2bf(a) | ((unsigned int)f2bf(b) << 16);
}
static __device__ __forceinline__ void unpackHL_g(const unsigned int* __restrict__ p,
                                                  short8v& hi, short8v& lo) {
  const uint4 a = *(const uint4*)p;
  const uint4 b = *(const uint4*)(p + 4);
  union { unsigned int u[4]; short8v s; } H, L;
  H.u[0] = (a.x & 0xffffu) | (a.y << 16);
  H.u[1] = (a.z & 0xffffu) | (a.w << 16);
  H.u[2] = (b.x & 0xffffu) | (b.y << 16);
  H.u[3] = (b.z & 0xffffu) | (b.w << 16);
  L.u[0] = (a.x >> 16) | (a.y & 0xffff0000u);
  L.u[1] = (a.z >> 16) | (a.w & 0xffff0000u);
  L.u[2] = (b.x >> 16) | (b.y & 0xffff0000u);
  L.u[3] = (b.z >> 16) | (b.w & 0xffff0000u);
  hi = H.s;
  lo = L.s;
}

// ---------------------------------------------------------------------------
// Edge conversion (int32/int64 auto-detect) + dst-degree histogram.
// atomicAdd return value = edge's rank within its dst-bucket; pack
// edata[e] = { dst | rank<<16 , src }. deg must be pre-zeroed (memset).
// ---------------------------------------------------------------------------
__global__ __launch_bounds__(256) void convert_count_k(const int* __restrict__ ei,
                                                       uint2* __restrict__ edata,
                                                       int* __restrict__ deg) {
  __shared__ int s_is64;
  if (threadIdx.x == 0) {
    int nz = 0;
#pragma unroll
    for (int k = 0; k < 64; ++k) nz |= ei[2 * k + 1];
    s_is64 = (nz == 0) ? 1 : 0;
  }
  __syncthreads();
  const int is64 = s_is64;
  const int e = blockIdx.x * 256 + threadIdx.x;
  if (e < N_EDGES) {
    int s, d;
    if (is64) {
      const uint2 sv = ((const uint2*)ei)[e];            // 8B load, low word = src
      const uint2 dv = ((const uint2*)ei)[N_EDGES + e];  // 8B load, low word = dst
      s = (int)sv.x;
      d = (int)dv.x;
    } else {
      s = ei[e];
      d = ei[N_EDGES + e];
    }
    const int r = atomicAdd(&deg[d], 1);  // rank within bucket
    const uint2 t = {(unsigned int)d | ((unsigned int)r << 16), (unsigned int)s};
    edata[e] = t;
  }
}

// ---------------------------------------------------------------------------
// Parallel 3-phase exclusive scan over deg (bsum / bscan / bfinal+dinv).
// ---------------------------------------------------------------------------
__global__ __launch_bounds__(256) void bsum_k(const int* __restrict__ deg,
                                              int* __restrict__ bsum) {
  const int i = blockIdx.x * 256 + threadIdx.x;
  int v = (i < N_NODES) ? deg[i] : 0;
#pragma unroll
  for (int off = 32; off > 0; off >>= 1) v += __shfl_down(v, off, 64);
  __shared__ int ws[4];
  if ((threadIdx.x & 63) == 0) ws[threadIdx.x >> 6] = v;
  __syncthreads();
  if (threadIdx.x == 0) bsum[blockIdx.x] = ws[0] + ws[1] + ws[2] + ws[3];
}

__global__ __launch_bounds__(256) void bscan_k(const int* __restrict__ bsum,
                                               int* __restrict__ boff) {
  __shared__ int s[256];
  const int t = threadIdx.x;
  const int v = (t < NBLK) ? bsum[t] : 0;
  s[t] = v;
  __syncthreads();
  for (int off = 1; off < 256; off <<= 1) {
    const int tmp = (t >= off) ? s[t - off] : 0;
    __syncthreads();
    s[t] += tmp;
    __syncthreads();
  }
  if (t < NBLK) boff[t] = s[t] - v;
}

__global__ __launch_bounds__(256) void bfinal_k(const int* __restrict__ deg,
                                                const int* __restrict__ boff,
                                                int* __restrict__ rowstart,
                                                float* __restrict__ dinv) {
  __shared__ int s[256];
  const int t = threadIdx.x;
  const int i = blockIdx.x * 256 + t;
  const int d = (i < N_NODES) ? deg[i] : 0;
  s[t] = d;
  __syncthreads();
  for (int off = 1; off < 256; off <<= 1) {
    const int tmp = (t >= off) ? s[t - off] : 0;
    __syncthreads();
    s[t] += tmp;
    __syncthreads();
  }
  const int run = boff[blockIdx.x] + s[t] - d;
  if (i < N_NODES) {
    rowstart[i] = run;
    dinv[i] = rsqrtf((float)d + 1.0f);
    if (i == N_NODES - 1) rowstart[N_NODES] = run + d;
  }
}

// ---------------------------------------------------------------------------
// XCD-partitioned, atomic-free CSR fill (partition p = bx&7 => one dst-range
// per XCD; bucket-contiguous csr lines coalesce in that XCD's L2).
// ---------------------------------------------------------------------------
__global__ __launch_bounds__(256) void fill_csr_part_k(const uint2* __restrict__ edata,
                                                       const int* __restrict__ rowstart,
                                                       int* __restrict__ csr_src) {
  const int p = blockIdx.x & 7;
  const int e = (blockIdx.x >> 3) * 256 + threadIdx.x;
  if (e < N_EDGES) {
    const uint2 t = edata[e];
    const int d = t.x & 0xffff;
    const int r = t.x >> 16;
    if (d / 6250 == p) csr_src[rowstart[d] + r] = (int)t.y;
  }
}

// ---------------------------------------------------------------------------
// Fused operand conversion: blocks [0,6250) convert x -> packed bf16;
// [6250,6378) split W1 -> HL; [6378,6506) split W2 -> HL.
// ---------------------------------------------------------------------------
__global__ __launch_bounds__(256) void conv_all_k(const float* __restrict__ x,
                                                  unsigned int* __restrict__ xbf,
                                                  const float* __restrict__ W1,
                                                  unsigned int* __restrict__ w1hl,
                                                  const float* __restrict__ W2,
                                                  unsigned int* __restrict__ w2hl) {
  const int b = blockIdx.x;
  if (b < XCONV_BLKS) {
    const int i = b * 256 + threadIdx.x;  // over N*C/4 float4s
    const float4 f = *(const float4*)(x + (long)i * 4);
    uint2 u = {packBF2(f.x, f.y), packBF2(f.z, f.w)};
    *(uint2*)(xbf + (long)i * 2) = u;
  } else if (b < XCONV_BLKS + WCONV_BLKS) {
    const int i = (b - XCONV_BLKS) * 256 + threadIdx.x;
    w1hl[i] = packHL(W1[i]);
  } else {
    const int i = (b - XCONV_BLKS - WCONV_BLKS) * 256 + threadIdx.x;
    w2hl[i] = packHL(W2[i]);
  }
}

// ---------------------------------------------------------------------------
// FUSED both-layer GEMM: per 64-node block,
//   GEMM1: h1 = relu(aggx @ W1^T + b1)   (K=128, M=256) -> LDS (bf16 packed)
//   GEMM2: h2 = h1 @ W2^T                (K=256, M=128) -> global bf16 packed
// aggx staged in LDS once; h1 NEVER touches HBM. W1/W2 HL from L2 (262 KB).
// Swapped MFMA operand order (m89-verified): lane's 4 acc = 4 consecutive m
// for one n. h1s row stride 132 u32 -> 2-4-way bank aliasing only.
// ---------------------------------------------------------------------------
__global__ __launch_bounds__(256) void gemm_fused_k(
    const unsigned int* __restrict__ X,     // aggx bf16-packed [N][64]
    const unsigned int* __restrict__ W1HL,  // [256][128] HL
    const float* __restrict__ b1,
    const unsigned int* __restrict__ W2HL,  // [128][256] HL
    unsigned int* __restrict__ outBF) {     // h2 bf16-packed [N][64]
  constexpr int KP1 = 68;   // aggx LDS row stride (64 + 4 pad)
  constexpr int HP = 132;   // h1 LDS row stride (128 + 4 pad)
  __shared__ unsigned int xs[64 * KP1];   // 17.4 KB
  __shared__ unsigned int h1s[64 * HP];   // 33.8 KB

  const int tid = threadIdx.x;
  const int w = tid >> 6;
  const int l = tid & 63;
  const long nbase = (long)blockIdx.x * 64;
  const int kg = (l >> 4) * 8;
  const int lr = l & 15;
  const int mq0 = (l >> 4) * 4;

  // ---- Stage aggx tile: 64 rows x 64 u32 ----
#pragma unroll
  for (int i = 0; i < 4; ++i) {
    const int idx = (tid + i * 256) * 4;
    const int row = idx >> 6, col = idx & 63;
    long gr = nbase + row;
    if (gr > N_NODES - 1) gr = N_NODES - 1;  // clamp; final stores guarded
    const uint4 v = *(const uint4*)(X + gr * 64 + col);
    *(uint4*)(xs + row * KP1 + col) = v;
  }
  __syncthreads();

  // ---- GEMM1: wave w owns m in [w*64, w*64+64), K=128 ----
  {
    const int m0w = w * 64;
    f32x4 acc[4][4];
#pragma unroll
    for (int nt = 0; nt < 4; ++nt)
#pragma unroll
      for (int mt = 0; mt < 4; ++mt) acc[nt][mt] = {0.0f, 0.0f, 0.0f, 0.0f};

#pragma unroll
    for (int ks = 0; ks < 4; ++ks) {
      const int ko = ks * 32 + kg;
      short8v wHi[4], wLo[4];
#pragma unroll
      for (int mt = 0; mt < 4; ++mt)
        unpackHL_g(W1HL + (long)(m0w + mt * 16 + lr) * IN_C + ko, wHi[mt], wLo[mt]);
#pragma unroll
      for (int nt = 0; nt < 4; ++nt) {
        const short8v xb = *(const short8v*)(xs + (nt * 16 + lr) * KP1 + ko / 2);
#pragma unroll
        for (int mt = 0; mt < 4; ++mt) {
          acc[nt][mt] = __builtin_amdgcn_mfma_f32_16x16x32_bf16(wHi[mt], xb,
                                                               acc[nt][mt], 0, 0, 0);
          acc[nt][mt] = __builtin_amdgcn_mfma_f32_16x16x32_bf16(wLo[mt], xb,
                                                               acc[nt][mt], 0, 0, 0);
        }
      }
    }

    // Epilogue 1: bias + relu -> packed bf16 into LDS h1s
#pragma unroll
    for (int nt = 0; nt < 4; ++nt) {
      const int nl = nt * 16 + lr;
#pragma unroll
      for (int mt = 0; mt < 4; ++mt) {
        const int mq = m0w + mt * 16 + mq0;
        const float4 bv = *(const float4*)(b1 + mq);
        const float v0 = fmaxf(acc[nt][mt][0] + bv.x, 0.0f);
        const float v1 = fmaxf(acc[nt][mt][1] + bv.y, 0.0f);
        const float v2 = fmaxf(acc[nt][mt][2] + bv.z, 0.0f);
        const float v3 = fmaxf(acc[nt][mt][3] + bv.w, 0.0f);
        uint2 o = {packBF2(v0, v1), packBF2(v2, v3)};
        *(uint2*)(h1s + nl * HP + mq / 2) = o;
      }
    }
  }
  __syncthreads();

  // ---- GEMM2: wave w owns m in [w*32, w*32+32), K=256 from LDS h1s ----
  {
    const int m0w = w * 32;
    f32x4 acc[4][2];
#pragma unroll
    for (int nt = 0; nt < 4; ++nt)
#pragma unroll
      for (int mt = 0; mt < 2; ++mt) acc[nt][mt] = {0.0f, 0.0f, 0.0f, 0.0f};

#pragma unroll
    for (int ks = 0; ks < 8; ++ks) {
      const int ko = ks * 32 + kg;
      short8v wHi[2], wLo[2];
#pragma unroll
      for (int mt = 0; mt < 2; ++mt)
        unpackHL_g(W2HL + (long)(m0w + mt * 16 + lr) * HID_C + ko, wHi[mt], wLo[mt]);
#pragma unroll
      for (int nt = 0; nt < 4; ++nt) {
        const short8v xb = *(const short8v*)(h1s + (nt * 16 + lr) * HP + ko / 2);
#pragma unroll
        for (int mt = 0; mt < 2; ++mt) {
          acc[nt][mt] = __builtin_amdgcn_mfma_f32_16x16x32_bf16(wHi[mt], xb,
                                                               acc[nt][mt], 0, 0, 0);
          acc[nt][mt] = __builtin_amdgcn_mfma_f32_16x16x32_bf16(wLo[mt], xb,
                                                               acc[nt][mt], 0, 0, 0);
        }
      }
    }

    // Epilogue 2: packed bf16 h2 to global
#pragma unroll
    for (int nt = 0; nt < 4; ++nt) {
      const long n = nbase + nt * 16 + lr;
      if (n < N_NODES) {
#pragma unroll
        for (int mt = 0; mt < 2; ++mt) {
          const int mq = m0w + mt * 16 + mq0;
          uint2 o = {packBF2(acc[nt][mt][0], acc[nt][mt][1]),
                     packBF2(acc[nt][mt][2], acc[nt][mt][3])};
          *(uint2*)(outBF + n * (OUT_C / 2) + mq / 2) = o;
        }
      }
    }
  }
}

// ---------------------------------------------------------------------------
// Gather-aggregate (one wave per destination node) over PACKED-BF16 rows.
// Lane reads 1 u32 = 2 channels per row. 8-edge unroll for MLP.
// OUT_BF: write packed bf16 u32 (feeds fused GEMM). Else fp32 (+bias) final.
// ---------------------------------------------------------------------------
template <int C, bool HAS_BIAS, bool OUT_BF>
__global__ __launch_bounds__(256) void gather_k(const int* __restrict__ rowstart,
                                                const int* __restrict__ csr_src,
                                                const float* __restrict__ dinv,
                                                const unsigned int* __restrict__ hbf,
                                                const float* __restrict__ bias,
                                                float* __restrict__ out,
                                                unsigned int* __restrict__ outBF) {
  const int v = (blockIdx.x * 256 + threadIdx.x) >> 6;
  if (v >= N_NODES) return;
  const int lane = threadIdx.x & 63;
  constexpr int CW = C / 2;  // u32 words per row
  const int rs = rowstart[v];
  const int re = rowstart[v + 1];
  const float dv = dinv[v];

  float a0 = 0.0f, a1 = 0.0f;

  int e = rs;
  for (; e + 7 < re; e += 8) {
    int s[8];
    float nn[8];
    unsigned int r[8];
#pragma unroll
    for (int j = 0; j < 8; ++j) s[j] = csr_src[e + j];
#pragma unroll
    for (int j = 0; j < 8; ++j) nn[j] = dv * dinv[s[j]];
#pragma unroll
    for (int j = 0; j < 8; ++j) r[j] = hbf[(long)s[j] * CW + lane];
#pragma unroll
    for (int j = 0; j < 8; ++j) {
      a0 += nn[j] * bf2f((unsigned short)r[j]);
      a1 += nn[j] * bf2f((unsigned short)(r[j] >> 16));
    }
  }
  for (; e + 3 < re; e += 4) {
    int s[4];
    float nn[4];
    unsigned int r[4];
#pragma unroll
    for (int j = 0; j < 4; ++j) s[j] = csr_src[e + j];
#pragma unroll
    for (int j = 0; j < 4; ++j) nn[j] = dv * dinv[s[j]];
#pragma unroll
    for (int j = 0; j < 4; ++j) r[j] = hbf[(long)s[j] * CW + lane];
#pragma unroll
    for (int j = 0; j < 4; ++j) {
      a0 += nn[j] * bf2f((unsigned short)r[j]);
      a1 += nn[j] * bf2f((unsigned short)(r[j] >> 16));
    }
  }
  for (; e < re; ++e) {
    const int s0 = csr_src[e];
    const float n0 = dv * dinv[s0];
    const unsigned int r0 = hbf[(long)s0 * CW + lane];
    a0 += n0 * bf2f((unsigned short)r0);
    a1 += n0 * bf2f((unsigned short)(r0 >> 16));
  }

  const float s2 = dv * dv;
  const unsigned int hv = hbf[(long)v * CW + lane];
  float o0 = s2 * bf2f((unsigned short)hv) + a0;
  float o1 = s2 * bf2f((unsigned short)(hv >> 16)) + a1;
  if (HAS_BIAS) {
    const float2 bv = *(const float2*)(bias + lane * 2);
    o0 += bv.x;
    o1 += bv.y;
  }
  if (OUT_BF) {
    outBF[(long)v * CW + lane] = packBF2(o0, o1);
  } else {
    const float2 o = {o0, o1};
    *(float2*)(out + (long)v * CW * 2 + lane * 2) = o;
  }
}

// ---------------------------------------------------------------------------
extern "C" void kernel_launch(void* const* d_in, const int* in_sizes, int n_in,
                              void* d_out, int out_size, void* d_ws, size_t ws_size,
                              hipStream_t stream) {
  (void)in_sizes; (void)n_in; (void)out_size; (void)ws_size;

  const float* x  = (const float*)d_in[0];
  const int*   ei = (const int*)d_in[1];
  const float* W1 = (const float*)d_in[2];
  const float* b1 = (const float*)d_in[3];
  const float* W2 = (const float*)d_in[4];
  const float* b2 = (const float*)d_in[5];
  float* out = (float*)d_out;

  // Workspace layout (bytes):
  char* ws = (char*)d_ws;
  uint2* edata    = (uint2*)(ws + 0);          //  6.4 MB {dst|rank<<16, src}
  int*   csr_src  = (int*)(ws + 6400000);      //  3.2 MB
  int*   deg      = (int*)(ws + 9600000);      //  0.2 MB
  int*   rowstart = (int*)(ws + 9800000);      //  0.2 MB (N+1)
  float* dinv     = (float*)(ws + 10000016);   //  0.2 MB
  int*   bsum     = (int*)(ws + 10200016);
  int*   boff     = (int*)(ws + 10201040);
  unsigned int* w1hl   = (unsigned int*)(ws + 10300000);  // 131 KB
  unsigned int* w2hl   = (unsigned int*)(ws + 10500000);  // 131 KB
  unsigned int* aggxbf = (unsigned int*)(ws + 11000000);  // 12.8 MB (bf16 packed)
  unsigned int* h2bf   = (unsigned int*)(ws + 24000000);  // 12.8 MB (bf16 packed)
  unsigned int* xbf    = (unsigned int*)(ws + 91200000);  // 12.8 MB

  const int EB = (N_EDGES + 255) / 256;  // 3125
  const int GB = (N_NODES + 3) / 4;      // gather: 1 node/wave

  // ---- Graph preprocessing: CSR by destination + dinv ----
  hipMemsetAsync(deg, 0, N_NODES * sizeof(int), stream);
  convert_count_k<<<EB, 256, 0, stream>>>(ei, edata, deg);
  bsum_k<<<NBLK, 256, 0, stream>>>(deg, bsum);
  bscan_k<<<1, 256, 0, stream>>>(bsum, boff);
  bfinal_k<<<NBLK, 256, 0, stream>>>(deg, boff, rowstart, dinv);
  fill_csr_part_k<<<EB * NPART, 256, 0, stream>>>(edata, rowstart, csr_src);

  // ---- Fused operand conversions (x -> bf16, W1/W2 -> HL) ----
  conv_all_k<<<XCONV_BLKS + 2 * WCONV_BLKS, 256, 0, stream>>>(x, xbf, W1, w1hl,
                                                              W2, w2hl);

  // ---- Layer 1 gather: aggx = agg(x_bf16) (bf16 out) ----
  gather_k<IN_C, false, true><<<GB, 256, 0, stream>>>(
      rowstart, csr_src, dinv, xbf, nullptr, nullptr, aggxbf);

  // ---- Fused GEMM1+GEMM2: h2 = relu(aggx@W1^T + b1) @ W2^T (h1 stays in LDS)
  gemm_fused_k<<<(N_NODES + 63) / 64, 256, 0, stream>>>(aggxbf, w1hl, b1, w2hl,
                                                        h2bf);

  // ---- Layer 2 gather: out = agg(h2_bf16) + b2 ----
  gather_k<OUT_C, true, false><<<GB, 256, 0, stream>>>(
      rowstart, csr_src, dinv, h2bf, b2, out, nullptr);
}